// Round 18
// baseline (522.188 us; speedup 1.0000x reference)
//
#include <hip/hip_runtime.h>
#include <hip/hip_fp16.h>

#define NN 200000
#define NE 2000000
#define NG 10000

#define NPB 256                       // nodes per bucket (dst>>8)
#define NBKT 782                      // ceil(NN/NPB)
#define EPB 8192                      // edges per partition block
#define NPBLK 245                     // ceil(NE/EPB)
#define SCAN_N (NBKT * NPBLK)         // 191,590
#define SCAN_PAD 191592
#define NSB1 ((SCAN_N + 255) / 256)   // 749

typedef __fp16 h2 __attribute__((ext_vector_type(2)));

__device__ __forceinline__ void fadd(float* p, float v) {
    unsafeAtomicAdd(p, v);  // HW global_atomic_add_f32
}

__device__ __forceinline__ float fdot2(h2 a, h2 b, float c) {
#if __has_builtin(__builtin_amdgcn_fdot2)
    return __builtin_amdgcn_fdot2(a, b, c, false);
#else
    return c + (float)a.x * (float)b.x + (float)a.y * (float)b.y;
#endif
}

__device__ __forceinline__ h2 pk16(float a, float b) {
#if __has_builtin(__builtin_amdgcn_cvt_pkrtz)
    return __builtin_amdgcn_cvt_pkrtz(a, b);
#else
    h2 r;
    r.x = (__fp16)a;
    r.y = (__fp16)b;
    return r;
#endif
}

__device__ __forceinline__ float4 h16_load4(const __half* p) {
    uint2 r = *reinterpret_cast<const uint2*>(p);
    __half2 a = *reinterpret_cast<__half2*>(&r.x);
    __half2 b = *reinterpret_cast<__half2*>(&r.y);
    float2 f0 = __half22float2(a);
    float2 f1 = __half22float2(b);
    return make_float4(f0.x, f0.y, f1.x, f1.y);
}

__device__ __forceinline__ void h16_store4(__half* p, float4 v) {
    h2 a = pk16(v.x, v.y);
    h2 b = pk16(v.z, v.w);
    uint2 r;
    r.x = *reinterpret_cast<uint*>(&a);
    r.y = *reinterpret_cast<uint*>(&b);
    *reinterpret_cast<uint2*>(p) = r;
}

// ---------------- node embedding: h16 = x @ node_w + node_b  [N,14]->[N,32] fp16
__global__ __launch_bounds__(256) void k_node_embed(const float* __restrict__ x,
                                                    const float* __restrict__ w,
                                                    const float* __restrict__ b,
                                                    __half* __restrict__ h16) {
    __shared__ float sw[14 * 32];
    __shared__ float sb[32];
    for (int i = threadIdx.x; i < 14 * 32; i += 256) sw[i] = w[i];
    if (threadIdx.x < 32) sb[threadIdx.x] = b[threadIdx.x];
    __syncthreads();
    int n = blockIdx.x * 256 + threadIdx.x;
    if (n >= NN) return;
    float xi[14];
#pragma unroll
    for (int k = 0; k < 14; ++k) xi[k] = x[n * 14 + k];
#pragma unroll
    for (int c = 0; c < 32; c += 4) {
        float4 acc = make_float4(sb[c], sb[c + 1], sb[c + 2], sb[c + 3]);
#pragma unroll
        for (int k = 0; k < 14; ++k) {
            float xv = xi[k];
            acc.x += xv * sw[k * 32 + c + 0];
            acc.y += xv * sw[k * 32 + c + 1];
            acc.z += xv * sw[k * 32 + c + 2];
            acc.w += xv * sw[k * 32 + c + 3];
        }
        h16_store4(h16 + (size_t)n * 32 + c, acc);
    }
}

// ---------------- weight prep (once): fp16-pack MLP weights, pad j to 76
__global__ __launch_bounds__(256) void k_prep(const float* __restrict__ w1,
                                              const float* __restrict__ b1,
                                              const float* __restrict__ w2,
                                              uint* __restrict__ w1h,
                                              uint* __restrict__ w2p,
                                              float* __restrict__ b1p) {
    int i = blockIdx.x * 256 + threadIdx.x;
    if (i < 2 * 76 * 16) {
        int l = i / (76 * 16), r = i % (76 * 16);
        int j = r / 16, p = r % 16;
        float a = (j < 75) ? w1[l * 2400 + (2 * p) * 75 + j] : 0.f;
        float b = (j < 75) ? w1[l * 2400 + (2 * p + 1) * 75 + j] : 0.f;
        uint lo = __half_as_ushort(__float2half_rn(a));
        uint hi = __half_as_ushort(__float2half_rn(b));
        w1h[i] = lo | (hi << 16);
        return;
    }
    int i2 = i - 2 * 76 * 16;
    if (i2 >= 0 && i2 < 2 * 38 * 32) {
        int l = i2 / (38 * 32), r = i2 % (38 * 32);
        int jp = r / 32, k = r % 32;
        float a = w2[l * 2400 + (2 * jp) * 32 + k];
        float b = (2 * jp + 1 < 75) ? w2[l * 2400 + (2 * jp + 1) * 32 + k] : 0.f;
        uint lo = __half_as_ushort(__float2half_rn(a));
        uint hi = __half_as_ushort(__float2half_rn(b));
        w2p[i2] = lo | (hi << 16);
        return;
    }
    int i3 = i2 - 2 * 38 * 32;
    if (i3 >= 0 && i3 < 2 * 76) {
        int l = i3 / 76, j = i3 % 76;
        b1p[i3] = (j < 75) ? b1[l * 75 + j] : 0.f;
    }
}

// ================= bucket partition + per-bucket sort (once per launch) =========
__global__ __launch_bounds__(1024) void k_hist(const int* __restrict__ ei,
                                               int* __restrict__ counts) {
    __shared__ int hist[NBKT];
    for (int i = threadIdx.x; i < NBKT; i += 1024) hist[i] = 0;
    __syncthreads();
    int base = blockIdx.x * EPB;
#pragma unroll
    for (int k = 0; k < EPB / 1024; ++k) {
        int e = base + k * 1024 + threadIdx.x;
        if (e < NE) atomicAdd(&hist[ei[NE + e] >> 8], 1);
    }
    __syncthreads();
    for (int b = threadIdx.x; b < NBKT; b += 1024)
        counts[b * NPBLK + blockIdx.x] = hist[b];
}

__global__ __launch_bounds__(256) void k_scanA(int* __restrict__ data,
                                               int* __restrict__ part) {
    __shared__ int s[256];
    int tid = threadIdx.x;
    int i = blockIdx.x * 256 + tid;
    int v = (i < SCAN_N) ? data[i] : 0;
    s[tid] = v;
    __syncthreads();
    for (int off = 1; off < 256; off <<= 1) {
        int t = (tid >= off) ? s[tid - off] : 0;
        __syncthreads();
        s[tid] += t;
        __syncthreads();
    }
    if (i < SCAN_N) data[i] = s[tid] - v;
    if (tid == 255) part[blockIdx.x] = s[255];
}

__global__ __launch_bounds__(1024) void k_scanB(int* __restrict__ part) {
    __shared__ int s[1024];
    int tid = threadIdx.x;
    int v = (tid < NSB1) ? part[tid] : 0;
    s[tid] = v;
    __syncthreads();
    for (int off = 1; off < 1024; off <<= 1) {
        int t = (tid >= off) ? s[tid - off] : 0;
        __syncthreads();
        s[tid] += t;
        __syncthreads();
    }
    if (tid < NSB1) part[tid] = s[tid] - v;
}

__global__ __launch_bounds__(256) void k_scanC(int* __restrict__ data,
                                               const int* __restrict__ part) {
    int i = blockIdx.x * 256 + threadIdx.x;
    if (i < SCAN_N) data[i] += part[blockIdx.x];
}

// rec = { src | nl<<24, half2(ea0,ea1), half(ea2) }  — 1024 threads/block
__global__ __launch_bounds__(1024) void k_part_scatter(const int* __restrict__ ei,
                                                       const float* __restrict__ ea,
                                                       const int* __restrict__ counts,
                                                       uint3* __restrict__ tmp) {
    __shared__ int sbase[NBKT];
    __shared__ int scnt[NBKT];
    for (int i = threadIdx.x; i < NBKT; i += 1024) {
        sbase[i] = counts[i * NPBLK + blockIdx.x];
        scnt[i] = 0;
    }
    __syncthreads();
    int base = blockIdx.x * EPB;
#pragma unroll
    for (int k = 0; k < EPB / 1024; ++k) {
        int e = base + k * 1024 + threadIdx.x;
        if (e >= NE) continue;
        int dst = ei[NE + e];
        int bkt = dst >> 8;
        int nl = dst & 255;
        int r = atomicAdd(&scnt[bkt], 1);
        int src = ei[e];
        __half2 p01 = __floats2half2_rn(ea[e * 3 + 0], ea[e * 3 + 1]);
        __half p2 = __float2half_rn(ea[e * 3 + 2]);
        uint3 rec;
        rec.x = (uint)(src | (nl << 24));
        rec.y = *reinterpret_cast<const uint*>(&p01);
        rec.z = (uint)__half_as_ushort(p2);
        tmp[sbase[bkt] + r] = rec;
    }
}

// per-bucket LDS counting sort -> exact node-sorted recs2 + row_off
__global__ __launch_bounds__(512) void k_bucket_sort(const int* __restrict__ counts,
                                                     const uint3* __restrict__ tmp,
                                                     uint3* __restrict__ recs2,
                                                     int* __restrict__ row_off) {
    __shared__ int cnt[NPB];
    __shared__ int s[NPB];
    int tid = threadIdx.x;
    int b = blockIdx.x;
    int boff = counts[b * NPBLK];
    int bend = (b == NBKT - 1) ? NE : counts[(b + 1) * NPBLK];
    if (tid < NPB) cnt[tid] = 0;
    __syncthreads();
    for (int i = boff + tid; i < bend; i += 512)
        atomicAdd(&cnt[(tmp[i].x >> 24) & 255], 1);
    __syncthreads();
    int v = (tid < NPB) ? cnt[tid] : 0;
    if (tid < NPB) s[tid] = v;
    __syncthreads();
    for (int off = 1; off < 256; off <<= 1) {
        int t = (tid >= off && tid < NPB) ? s[tid - off] : 0;
        __syncthreads();
        if (tid < NPB) s[tid] += t;
        __syncthreads();
    }
    if (tid < NPB) {
        int excl = s[tid] - v;
        int n = b * NPB + tid;
        if (n < NN) row_off[n] = boff + excl;
        cnt[tid] = excl;  // becomes fill counter
    }
    if (b == NBKT - 1 && tid == 0) row_off[NN] = NE;
    __syncthreads();
    for (int i = boff + tid; i < bend; i += 512) {
        uint3 r = tmp[i];
        int nl = (r.x >> 24) & 255;
        int p = atomicAdd(&cnt[nl], 1);
        recs2[boff + p] = r;
    }
}

// shared helper: per-block BN affine preamble into LDS (sc,sh per channel)
__device__ __forceinline__ void bn_preamble(float* ssc, float* ssh, int apply,
                                            const float* in_stats,
                                            const float* in_g, const float* in_b) {
    if (threadIdx.x < 32) {
        float s = 1.f, t = 0.f;
        if (apply) {
            int cc = threadIdx.x;
            float mu = in_stats[cc] * (1.0f / NN);
            float var = in_stats[32 + cc] * (1.0f / NN) - mu * mu;
            s = in_g[cc] * rsqrtf(var + 1e-5f);
            t = in_b[cc] - mu * s;
        }
        ssc[threadIdx.x] = s;
        ssh[threadIdx.x] = t;
    }
}

// ---------------- exact-CSR gather aggregation: 8 thr/node, 8B fp16 z gathers.
// Applies h = APPLY ? relu(z*sc+sh) : z on the fly, and ADDS OWN NODE's h so
// the output zb holds the complete z0 = h[n] + sum_msgs (mlp reads only zb).
template <int APPLY>
__global__ __launch_bounds__(256) void k_aggregate(const int* __restrict__ row_off,
                                                   const uint3* __restrict__ recs,
                                                   const float* __restrict__ ew,
                                                   const float* __restrict__ eb,
                                                   const __half* __restrict__ h16,
                                                   const float* __restrict__ in_stats,
                                                   const float* __restrict__ in_g,
                                                   const float* __restrict__ in_b,
                                                   float* __restrict__ agg) {
    __shared__ float sw[96];
    __shared__ float sb[32];
    __shared__ float ssc[32], ssh[32];
    if (threadIdx.x < 96) sw[threadIdx.x] = ew[threadIdx.x];
    if (threadIdx.x < 32) sb[threadIdx.x] = eb[threadIdx.x];
    bn_preamble(ssc, ssh, APPLY, in_stats, in_g, in_b);
    __syncthreads();
    int t = blockIdx.x * 256 + threadIdx.x;
    int n = t >> 3;
    if (n >= NN) return;
    int c = (t & 7) * 4;  // 4 channels per thread
    float w0[4], w1[4], w2[4], bb[4], acc[4], sc4[4], sh4[4];
#pragma unroll
    for (int j = 0; j < 4; ++j) {
        w0[j] = sw[c + j];
        w1[j] = sw[32 + c + j];
        w2[j] = sw[64 + c + j];
        bb[j] = sb[c + j];
        sc4[j] = ssc[c + j];
        sh4[j] = ssh[c + j];
        acc[j] = 0.f;
    }
    int s0 = row_off[n], s1 = row_off[n + 1];
    int i = s0;
    for (; i + 2 <= s1; i += 2) {
        uint3 r0 = recs[i];
        uint3 r1 = recs[i + 1];
        int src0 = r0.x & 0x00FFFFFF;
        int src1 = r1.x & 0x00FFFFFF;
        uint2 ha = *(const uint2*)(h16 + (size_t)src0 * 32 + c);
        uint2 hb = *(const uint2*)(h16 + (size_t)src1 * 32 + c);
        float2 e01a = __half22float2(*reinterpret_cast<const __half2*>(&r0.y));
        float e2a = __half2float(__ushort_as_half((unsigned short)(r0.z & 0xFFFF)));
        float2 e01b = __half22float2(*reinterpret_cast<const __half2*>(&r1.y));
        float e2b = __half2float(__ushort_as_half((unsigned short)(r1.z & 0xFFFF)));
        float fa[4], fb[4];
        {
            float2 t0 = __half22float2(*reinterpret_cast<const __half2*>(&ha.x));
            float2 t1 = __half22float2(*reinterpret_cast<const __half2*>(&ha.y));
            fa[0] = t0.x; fa[1] = t0.y; fa[2] = t1.x; fa[3] = t1.y;
            float2 u0 = __half22float2(*reinterpret_cast<const __half2*>(&hb.x));
            float2 u1 = __half22float2(*reinterpret_cast<const __half2*>(&hb.y));
            fb[0] = u0.x; fb[1] = u0.y; fb[2] = u1.x; fb[3] = u1.y;
        }
#pragma unroll
        for (int j = 0; j < 4; ++j) {
            float va = fa[j], vb = fb[j];
            if (APPLY) {
                va = fmaxf(va * sc4[j] + sh4[j], 0.f);
                vb = fmaxf(vb * sc4[j] + sh4[j], 0.f);
            }
            float ma = va + bb[j] + e01a.x * w0[j] + e01a.y * w1[j] + e2a * w2[j];
            float mb = vb + bb[j] + e01b.x * w0[j] + e01b.y * w1[j] + e2b * w2[j];
            acc[j] += fmaxf(ma, 0.f) + fmaxf(mb, 0.f);
        }
    }
    if (i < s1) {
        uint3 r0 = recs[i];
        int src0 = r0.x & 0x00FFFFFF;
        uint2 ha = *(const uint2*)(h16 + (size_t)src0 * 32 + c);
        float2 e01a = __half22float2(*reinterpret_cast<const __half2*>(&r0.y));
        float e2a = __half2float(__ushort_as_half((unsigned short)(r0.z & 0xFFFF)));
        float2 t0 = __half22float2(*reinterpret_cast<const __half2*>(&ha.x));
        float2 t1 = __half22float2(*reinterpret_cast<const __half2*>(&ha.y));
        float fa[4] = {t0.x, t0.y, t1.x, t1.y};
#pragma unroll
        for (int j = 0; j < 4; ++j) {
            float va = fa[j];
            if (APPLY) va = fmaxf(va * sc4[j] + sh4[j], 0.f);
            float ma = va + bb[j] + e01a.x * w0[j] + e01a.y * w1[j] + e2a * w2[j];
            acc[j] += fmaxf(ma, 0.f);
        }
    }
    // add own node's h (affine) so zb = complete z0 = h[n] + agg
    {
        uint2 hn = *(const uint2*)(h16 + (size_t)n * 32 + c);
        float2 t0 = __half22float2(*reinterpret_cast<const __half2*>(&hn.x));
        float2 t1 = __half22float2(*reinterpret_cast<const __half2*>(&hn.y));
        float fn[4] = {t0.x, t0.y, t1.x, t1.y};
#pragma unroll
        for (int j = 0; j < 4; ++j) {
            float vn = fn[j];
            if (APPLY) vn = fmaxf(vn * sc4[j] + sh4[j], 0.f);
            acc[j] += vn;
        }
    }
    *(float4*)(agg + (size_t)n * 32 + c) = make_float4(acc[0], acc[1], acc[2], acc[3]);
}

// ---------------- fallback atomic scatter (only if ws too small)
__global__ __launch_bounds__(256) void k_edge_scatter(const int* __restrict__ ei,
                                                      const float* __restrict__ ea,
                                                      const float* __restrict__ ew,
                                                      const float* __restrict__ eb,
                                                      const __half* __restrict__ h16,
                                                      const float* __restrict__ in_stats,
                                                      const float* __restrict__ in_g,
                                                      const float* __restrict__ in_b,
                                                      int apply,
                                                      float* __restrict__ agg) {
    __shared__ float sw[96];
    __shared__ float sb[32];
    __shared__ float ssc[32], ssh[32];
    if (threadIdx.x < 96) sw[threadIdx.x] = ew[threadIdx.x];
    if (threadIdx.x < 32) sb[threadIdx.x] = eb[threadIdx.x];
    bn_preamble(ssc, ssh, apply, in_stats, in_g, in_b);
    __syncthreads();
    int t = blockIdx.x * 256 + threadIdx.x;
    int edge = t >> 3;
    if (edge >= NE) return;
    int c = (t & 7) * 4;
    int src = ei[edge];
    int dst = ei[NE + edge];
    float a0 = ea[edge * 3 + 0];
    float a1 = ea[edge * 3 + 1];
    float a2 = ea[edge * 3 + 2];
    float4 hs = h16_load4(h16 + (size_t)src * 32 + c);
    if (apply) {
        hs.x = fmaxf(hs.x * ssc[c + 0] + ssh[c + 0], 0.f);
        hs.y = fmaxf(hs.y * ssc[c + 1] + ssh[c + 1], 0.f);
        hs.z = fmaxf(hs.z * ssc[c + 2] + ssh[c + 2], 0.f);
        hs.w = fmaxf(hs.w * ssc[c + 3] + ssh[c + 3], 0.f);
    }
    float m0 = hs.x + sb[c + 0] + a0 * sw[c + 0] + a1 * sw[32 + c + 0] + a2 * sw[64 + c + 0];
    float m1 = hs.y + sb[c + 1] + a0 * sw[c + 1] + a1 * sw[32 + c + 1] + a2 * sw[64 + c + 1];
    float m2 = hs.z + sb[c + 2] + a0 * sw[c + 2] + a1 * sw[32 + c + 2] + a2 * sw[64 + c + 2];
    float m3 = hs.w + sb[c + 3] + a0 * sw[c + 3] + a1 * sw[32 + c + 3] + a2 * sw[64 + c + 3];
    float* o = agg + (size_t)dst * 32 + c;
    fadd(o + 0, fmaxf(m0, 0.f));
    fadd(o + 1, fmaxf(m1, 0.f));
    fadd(o + 2, fmaxf(m2, 0.f));
    fadd(o + 3, fmaxf(m3, 0.f));
}

// ---------------- own-node add for fallback path (zb += h_affine[n])
__global__ __launch_bounds__(256) void k_self_add(const __half* __restrict__ h16,
                                                  const float* __restrict__ in_stats,
                                                  const float* __restrict__ in_g,
                                                  const float* __restrict__ in_b,
                                                  int apply,
                                                  float* __restrict__ agg) {
    __shared__ float ssc[32], ssh[32];
    bn_preamble(ssc, ssh, apply, in_stats, in_g, in_b);
    __syncthreads();
    int i = blockIdx.x * 256 + threadIdx.x;
    if (i >= NN * 8) return;
    int c = (i & 7) * 4;
    float4 v = h16_load4(h16 + (size_t)i * 4);
    if (apply) {
        v.x = fmaxf(v.x * ssc[c + 0] + ssh[c + 0], 0.f);
        v.y = fmaxf(v.y * ssc[c + 1] + ssh[c + 1], 0.f);
        v.z = fmaxf(v.z * ssc[c + 2] + ssh[c + 2], 0.f);
        v.w = fmaxf(v.w * ssc[c + 3] + ssh[c + 3], 0.f);
    }
    float4 a = *(const float4*)(agg + (size_t)i * 4);
    *(float4*)(agg + (size_t)i * 4) = make_float4(a.x + v.x, a.y + v.y, a.z + v.z, a.w + v.w);
}

// ---------------- node MLP + fused BN stats; 2 threads/node (lane pair).
// Thread half=h computes hidden units j in [38h, 38h+38), partial acc[32];
// pair combines via shfl_xor(1); each thread stores its 16-channel half.
__global__ __launch_bounds__(256) void k_mlp_stats(__half* __restrict__ hio,
                                                   const float* __restrict__ agg,
                                                   const uint* __restrict__ w1h_u,
                                                   const float* __restrict__ b1p,
                                                   const uint* __restrict__ w2p_u,
                                                   const float* __restrict__ b2,
                                                   float* __restrict__ stats) {
    __shared__ float ls[4][64];
    const h2* w1h = reinterpret_cast<const h2*>(w1h_u);
    const h2* w2p = reinterpret_cast<const h2*>(w2p_u);
    int tid = threadIdx.x;
    int gid = blockIdx.x * 256 + tid;
    int n = gid >> 1;
    int half = gid & 1;
    bool valid = n < NN;
    h2 zp[16];
    float acc[32];
    if (valid) {
#pragma unroll
        for (int c = 0; c < 32; c += 4) {
            float4 av = *(const float4*)(agg + (size_t)n * 32 + c);
            zp[c / 2] = pk16(av.x, av.y);
            zp[c / 2 + 1] = pk16(av.z, av.w);
        }
    } else {
#pragma unroll
        for (int p = 0; p < 16; ++p) zp[p] = pk16(0.f, 0.f);
    }
    // bias only on half 0 (added once after combine)
#pragma unroll
    for (int k = 0; k < 32; ++k) acc[k] = half ? 0.f : b2[k];
    int jp0 = half * 19;
    for (int jp = jp0; jp < jp0 + 19; ++jp) {
        float t0a = b1p[2 * jp], t0b = 0.f;
        float t1a = b1p[2 * jp + 1], t1b = 0.f;
        const h2* r0 = w1h + (2 * jp) * 16;
        const h2* r1 = w1h + (2 * jp + 1) * 16;
#pragma unroll
        for (int p = 0; p < 8; ++p) {
            t0a = fdot2(zp[2 * p], r0[2 * p], t0a);
            t0b = fdot2(zp[2 * p + 1], r0[2 * p + 1], t0b);
            t1a = fdot2(zp[2 * p], r1[2 * p], t1a);
            t1b = fdot2(zp[2 * p + 1], r1[2 * p + 1], t1b);
        }
        float t0 = fmaxf(t0a + t0b, 0.f);
        float t1 = fmaxf(t1a + t1b, 0.f);
        h2 tp = pk16(t0, t1);
        const h2* c2 = w2p + jp * 32;
#pragma unroll
        for (int k = 0; k < 32; ++k) acc[k] = fdot2(tp, c2[k], acc[k]);
    }
    // combine lane pair: lanes 2t and 2t+1 hold partials of the same node
#pragma unroll
    for (int k = 0; k < 32; ++k) acc[k] += __shfl_xor(acc[k], 1);
    if (valid) {
        int cb = half * 16;  // this thread stores its 16-channel half
#pragma unroll
        for (int c = 0; c < 16; c += 4)
            h16_store4(hio + (size_t)n * 32 + cb + c,
                       make_float4(acc[cb + c], acc[cb + c + 1], acc[cb + c + 2], acc[cb + c + 3]));
    }
    // stats: contribute each node exactly once (half==0 threads)
    if (!valid || half) {
#pragma unroll
        for (int k = 0; k < 32; ++k) acc[k] = 0.f;
    }
    int wave = tid >> 6, lane = tid & 63;
#pragma unroll
    for (int k = 0; k < 32; ++k) {
        float sv = acc[k];
        float qv = sv * sv;
#pragma unroll
        for (int off = 1; off < 64; off <<= 1) {
            sv += __shfl_xor(sv, off);
            qv += __shfl_xor(qv, off);
        }
        if (lane == 0) {
            ls[wave][k] = sv;
            ls[wave][32 + k] = qv;
        }
    }
    __syncthreads();
    if (tid < 64)
        fadd(&stats[tid], ls[0][tid] + ls[1][tid] + ls[2][tid] + ls[3][tid]);
}

// ---------------- pool: batch sorted — affine+relu on the fly, flush per boundary
__global__ __launch_bounds__(256) void k_pool(const __half* __restrict__ h16,
                                              const int* __restrict__ batch,
                                              const float* __restrict__ in_stats,
                                              const float* __restrict__ in_g,
                                              const float* __restrict__ in_b,
                                              float* __restrict__ gsum,
                                              float* __restrict__ gcnt) {
    __shared__ float ssc[32], ssh[32];
    bn_preamble(ssc, ssh, 1, in_stats, in_g, in_b);
    __syncthreads();
    int gid = blockIdx.x * 256 + threadIdx.x;
    int nb = (gid >> 3) * 8;
    if (nb >= NN) return;
    int c = (gid & 7) * 4;
    bool lead = (gid & 7) == 0;
    float sc0 = ssc[c], sc1 = ssc[c + 1], sc2 = ssc[c + 2], sc3 = ssc[c + 3];
    float sh0 = ssh[c], sh1 = ssh[c + 1], sh2 = ssh[c + 2], sh3 = ssh[c + 3];
    float4 acc = make_float4(0.f, 0.f, 0.f, 0.f);
    float cnt = 0.f;
    int cur = batch[nb];
#pragma unroll
    for (int k = 0; k < 8; ++k) {
        int n = nb + k;
        if (n >= NN) break;
        int bg = batch[n];
        if (bg != cur) {
            float* o = gsum + (size_t)cur * 32 + c;
            fadd(o + 0, acc.x); fadd(o + 1, acc.y);
            fadd(o + 2, acc.z); fadd(o + 3, acc.w);
            if (lead) fadd(&gcnt[cur], cnt);
            acc = make_float4(0.f, 0.f, 0.f, 0.f);
            cnt = 0.f;
            cur = bg;
        }
        float4 v = h16_load4(h16 + (size_t)n * 32 + c);
        acc.x += fmaxf(v.x * sc0 + sh0, 0.f);
        acc.y += fmaxf(v.y * sc1 + sh1, 0.f);
        acc.z += fmaxf(v.z * sc2 + sh2, 0.f);
        acc.w += fmaxf(v.w * sc3 + sh3, 0.f);
        cnt += 1.f;
    }
    float* o = gsum + (size_t)cur * 32 + c;
    fadd(o + 0, acc.x); fadd(o + 1, acc.y);
    fadd(o + 2, acc.z); fadd(o + 3, acc.w);
    if (lead) fadd(&gcnt[cur], cnt);
}

__global__ __launch_bounds__(256) void k_head(const float* __restrict__ gsum,
                                              const float* __restrict__ gcnt,
                                              const float* __restrict__ l1w,
                                              const float* __restrict__ l1b,
                                              const float* __restrict__ l2w,
                                              const float* __restrict__ l2b,
                                              float* __restrict__ out) {
    __shared__ float s1[32 * 16], sb1[16], s2[16 * 2], sb2[2];
    for (int i = threadIdx.x; i < 512; i += 256) s1[i] = l1w[i];
    if (threadIdx.x < 16) sb1[threadIdx.x] = l1b[threadIdx.x];
    if (threadIdx.x < 32) s2[threadIdx.x] = l2w[threadIdx.x];
    if (threadIdx.x < 2) sb2[threadIdx.x] = l2b[threadIdx.x];
    __syncthreads();
    int gi = blockIdx.x * 256 + threadIdx.x;
    if (gi >= NG) return;
    float inv = 1.0f / fmaxf(gcnt[gi], 1.0f);
    float gm[32];
#pragma unroll
    for (int c = 0; c < 32; c += 4) {
        float4 v = *(const float4*)(gsum + (size_t)gi * 32 + c);
        gm[c + 0] = v.x * inv;
        gm[c + 1] = v.y * inv;
        gm[c + 2] = v.z * inv;
        gm[c + 3] = v.w * inv;
    }
    float a[16];
#pragma unroll
    for (int j = 0; j < 16; ++j) {
        float t = sb1[j];
#pragma unroll
        for (int c = 0; c < 32; ++c) t += gm[c] * s1[c * 16 + j];
        a[j] = fmaxf(t, 0.f);
    }
    float o0 = sb2[0], o1 = sb2[1];
#pragma unroll
    for (int j = 0; j < 16; ++j) {
        o0 += a[j] * s2[j * 2 + 0];
        o1 += a[j] * s2[j * 2 + 1];
    }
    out[gi * 2 + 0] = o0;
    out[gi * 2 + 1] = o1;
}

extern "C" void kernel_launch(void* const* d_in, const int* in_sizes, int n_in,
                              void* d_out, int out_size, void* d_ws, size_t ws_size,
                              hipStream_t stream) {
    const float* x = (const float*)d_in[0];
    const int* ei = (const int*)d_in[1];
    const float* ea = (const float*)d_in[2];
    const int* batch = (const int*)d_in[3];
    const float* node_w = (const float*)d_in[4];
    const float* node_b = (const float*)d_in[5];
    const float* edge_w = (const float*)d_in[6];
    const float* edge_b = (const float*)d_in[7];
    const float* w1 = (const float*)d_in[8];
    const float* b1 = (const float*)d_in[9];
    const float* w2 = (const float*)d_in[10];
    const float* b2 = (const float*)d_in[11];
    const float* bng = (const float*)d_in[12];
    const float* bnb = (const float*)d_in[13];
    const float* l1w = (const float*)d_in[14];
    const float* l1b = (const float*)d_in[15];
    const float* l2w = (const float*)d_in[16];
    const float* l2b = (const float*)d_in[17];
    float* out = (float*)d_out;

    // workspace layout (float units)
    float* base = (float*)d_ws;
    __half* h16 = (__half*)base;                   // NN*32 halves = 3.2M floats (z16)
    float* zb = base + 3200000;                    // NN*32 fp32 (z0; aliases tmp)
    float* gsum = zb + (size_t)NN * 32;            // NG*32
    float* gcnt = gsum + (size_t)NG * 32;          // NG
    float* stats = gcnt + NG;                      // 2*64 (per layer)
    uint* w1h = (uint*)(stats + 128);              // 2*76*16 = 2432
    uint* w2p = w1h + 2 * 76 * 16;                 // 2*38*32 = 2432
    float* b1p = (float*)(w2p + 2 * 38 * 32);      // 152
    int* counts = (int*)(b1p + 152);               // SCAN_PAD
    int* part = counts + SCAN_PAD;                 // 1024
    int* row_off = part + 1024;                    // NN+4
    uint3* recs2 = (uint3*)(row_off + NN + 4);     // NE*3 uints
    uint3* tmp = (uint3*)zb;                       // NE*3 = 6.0M <= 6.4M floats

    size_t need_f = 3200000 + (size_t)NN * 32 + (size_t)NG * 33 + 128 + 2432 + 2432 + 152 +
                    SCAN_PAD + 1024 + ((size_t)NN + 4) + (size_t)NE * 3;
    bool use_fast = ws_size >= need_f * 4;

    if (use_fast) {
        k_hist<<<NPBLK, 1024, 0, stream>>>(ei, counts);
        k_scanA<<<NSB1, 256, 0, stream>>>(counts, part);
        k_scanB<<<1, 1024, 0, stream>>>(part);
        k_scanC<<<NSB1, 256, 0, stream>>>(counts, part);
        k_part_scatter<<<NPBLK, 1024, 0, stream>>>(ei, ea, counts, tmp);
        k_bucket_sort<<<NBKT, 512, 0, stream>>>(counts, tmp, recs2, row_off);
    }
    k_prep<<<(2 * 76 * 16 + 2 * 38 * 32 + 2 * 76 + 255) / 256, 256, 0, stream>>>(
        w1, b1, w2, w1h, w2p, b1p);

    k_node_embed<<<(NN + 255) / 256, 256, 0, stream>>>(x, node_w, node_b, h16);

    (void)hipMemsetAsync(stats, 0, 128 * sizeof(float), stream);

    for (int l = 0; l < 2; ++l) {
        int apply = (l > 0) ? 1 : 0;
        const float* prev_stats = (l > 0) ? (stats + (l - 1) * 64) : stats;
        const float* ig = (l > 0) ? (bng + (l - 1) * 32) : bng;  // unused when apply=0
        const float* ib = (l > 0) ? (bnb + (l - 1) * 32) : bnb;
        if (use_fast) {
            if (apply)
                k_aggregate<1><<<(NN * 8 + 255) / 256, 256, 0, stream>>>(row_off, recs2,
                                                                         edge_w, edge_b, h16,
                                                                         prev_stats, ig, ib, zb);
            else
                k_aggregate<0><<<(NN * 8 + 255) / 256, 256, 0, stream>>>(row_off, recs2,
                                                                         edge_w, edge_b, h16,
                                                                         prev_stats, ig, ib, zb);
        } else {
            (void)hipMemsetAsync(zb, 0, (size_t)NN * 32 * sizeof(float), stream);
            k_edge_scatter<<<(NE * 8) / 256, 256, 0, stream>>>(ei, ea, edge_w, edge_b, h16,
                                                               prev_stats, ig, ib, apply, zb);
            k_self_add<<<(NN * 8 + 255) / 256, 256, 0, stream>>>(h16, prev_stats, ig, ib,
                                                                 apply, zb);
        }
        k_mlp_stats<<<(NN * 2 + 255) / 256, 256, 0, stream>>>(h16, zb, w1h + l * 76 * 16,
                                                              b1p + l * 76, w2p + l * 38 * 32,
                                                              b2 + l * 32, stats + l * 64);
    }

    (void)hipMemsetAsync(gsum, 0, (size_t)(NG * 33) * sizeof(float), stream);
    k_pool<<<(NN + 255) / 256, 256, 0, stream>>>(h16, batch, stats + 64, bng + 32, bnb + 32,
                                                 gsum, gcnt);
    k_head<<<(NG + 255) / 256, 256, 0, stream>>>(gsum, gcnt, l1w, l1b, l2w, l2b, out);
}

// Round 19
// 306.041 us; speedup vs baseline: 1.7063x; 1.7063x over previous
//
#include <hip/hip_runtime.h>
#include <hip/hip_fp16.h>

#define NN 200000
#define NE 2000000
#define NG 10000

#define NPB 256                       // nodes per bucket (dst>>8)
#define NBKT 782                      // ceil(NN/NPB)
#define EPB 8192                      // edges per partition block
#define NPBLK 245                     // ceil(NE/EPB)
#define SCAN_N (NBKT * NPBLK)         // 191,590
#define SCAN_PAD 191592
#define NSB1 ((SCAN_N + 255) / 256)   // 749

typedef __fp16 h2 __attribute__((ext_vector_type(2)));

__device__ __forceinline__ void fadd(float* p, float v) {
    unsafeAtomicAdd(p, v);  // HW global_atomic_add_f32
}

__device__ __forceinline__ float fdot2(h2 a, h2 b, float c) {
#if __has_builtin(__builtin_amdgcn_fdot2)
    return __builtin_amdgcn_fdot2(a, b, c, false);
#else
    return c + (float)a.x * (float)b.x + (float)a.y * (float)b.y;
#endif
}

__device__ __forceinline__ h2 pk16(float a, float b) {
#if __has_builtin(__builtin_amdgcn_cvt_pkrtz)
    return __builtin_amdgcn_cvt_pkrtz(a, b);
#else
    h2 r;
    r.x = (__fp16)a;
    r.y = (__fp16)b;
    return r;
#endif
}

__device__ __forceinline__ float4 h16_load4(const __half* p) {
    uint2 r = *reinterpret_cast<const uint2*>(p);
    __half2 a = *reinterpret_cast<__half2*>(&r.x);
    __half2 b = *reinterpret_cast<__half2*>(&r.y);
    float2 f0 = __half22float2(a);
    float2 f1 = __half22float2(b);
    return make_float4(f0.x, f0.y, f1.x, f1.y);
}

__device__ __forceinline__ void h16_store4(__half* p, float4 v) {
    h2 a = pk16(v.x, v.y);
    h2 b = pk16(v.z, v.w);
    uint2 r;
    r.x = *reinterpret_cast<uint*>(&a);
    r.y = *reinterpret_cast<uint*>(&b);
    *reinterpret_cast<uint2*>(p) = r;
}

// ---------------- node embedding: h16 = x @ node_w + node_b  [N,14]->[N,32] fp16
__global__ __launch_bounds__(256) void k_node_embed(const float* __restrict__ x,
                                                    const float* __restrict__ w,
                                                    const float* __restrict__ b,
                                                    __half* __restrict__ h16) {
    __shared__ float sw[14 * 32];
    __shared__ float sb[32];
    for (int i = threadIdx.x; i < 14 * 32; i += 256) sw[i] = w[i];
    if (threadIdx.x < 32) sb[threadIdx.x] = b[threadIdx.x];
    __syncthreads();
    int n = blockIdx.x * 256 + threadIdx.x;
    if (n >= NN) return;
    float xi[14];
#pragma unroll
    for (int k = 0; k < 14; ++k) xi[k] = x[n * 14 + k];
#pragma unroll
    for (int c = 0; c < 32; c += 4) {
        float4 acc = make_float4(sb[c], sb[c + 1], sb[c + 2], sb[c + 3]);
#pragma unroll
        for (int k = 0; k < 14; ++k) {
            float xv = xi[k];
            acc.x += xv * sw[k * 32 + c + 0];
            acc.y += xv * sw[k * 32 + c + 1];
            acc.z += xv * sw[k * 32 + c + 2];
            acc.w += xv * sw[k * 32 + c + 3];
        }
        h16_store4(h16 + (size_t)n * 32 + c, acc);
    }
}

// ---------------- weight prep (once): fp16-pack MLP weights, pad j to 76
__global__ __launch_bounds__(256) void k_prep(const float* __restrict__ w1,
                                              const float* __restrict__ b1,
                                              const float* __restrict__ w2,
                                              uint* __restrict__ w1h,
                                              uint* __restrict__ w2p,
                                              float* __restrict__ b1p) {
    int i = blockIdx.x * 256 + threadIdx.x;
    if (i < 2 * 76 * 16) {
        int l = i / (76 * 16), r = i % (76 * 16);
        int j = r / 16, p = r % 16;
        float a = (j < 75) ? w1[l * 2400 + (2 * p) * 75 + j] : 0.f;
        float b = (j < 75) ? w1[l * 2400 + (2 * p + 1) * 75 + j] : 0.f;
        uint lo = __half_as_ushort(__float2half_rn(a));
        uint hi = __half_as_ushort(__float2half_rn(b));
        w1h[i] = lo | (hi << 16);
        return;
    }
    int i2 = i - 2 * 76 * 16;
    if (i2 >= 0 && i2 < 2 * 38 * 32) {
        int l = i2 / (38 * 32), r = i2 % (38 * 32);
        int jp = r / 32, k = r % 32;
        float a = w2[l * 2400 + (2 * jp) * 32 + k];
        float b = (2 * jp + 1 < 75) ? w2[l * 2400 + (2 * jp + 1) * 32 + k] : 0.f;
        uint lo = __half_as_ushort(__float2half_rn(a));
        uint hi = __half_as_ushort(__float2half_rn(b));
        w2p[i2] = lo | (hi << 16);
        return;
    }
    int i3 = i2 - 2 * 38 * 32;
    if (i3 >= 0 && i3 < 2 * 76) {
        int l = i3 / 76, j = i3 % 76;
        b1p[i3] = (j < 75) ? b1[l * 75 + j] : 0.f;
    }
}

// ================= bucket partition + per-bucket sort (once per launch) =========
__global__ __launch_bounds__(1024) void k_hist(const int* __restrict__ ei,
                                               int* __restrict__ counts) {
    __shared__ int hist[NBKT];
    for (int i = threadIdx.x; i < NBKT; i += 1024) hist[i] = 0;
    __syncthreads();
    int base = blockIdx.x * EPB;
#pragma unroll
    for (int k = 0; k < EPB / 1024; ++k) {
        int e = base + k * 1024 + threadIdx.x;
        if (e < NE) atomicAdd(&hist[ei[NE + e] >> 8], 1);
    }
    __syncthreads();
    for (int b = threadIdx.x; b < NBKT; b += 1024)
        counts[b * NPBLK + blockIdx.x] = hist[b];
}

__global__ __launch_bounds__(256) void k_scanA(int* __restrict__ data,
                                               int* __restrict__ part) {
    __shared__ int s[256];
    int tid = threadIdx.x;
    int i = blockIdx.x * 256 + tid;
    int v = (i < SCAN_N) ? data[i] : 0;
    s[tid] = v;
    __syncthreads();
    for (int off = 1; off < 256; off <<= 1) {
        int t = (tid >= off) ? s[tid - off] : 0;
        __syncthreads();
        s[tid] += t;
        __syncthreads();
    }
    if (i < SCAN_N) data[i] = s[tid] - v;
    if (tid == 255) part[blockIdx.x] = s[255];
}

__global__ __launch_bounds__(1024) void k_scanB(int* __restrict__ part) {
    __shared__ int s[1024];
    int tid = threadIdx.x;
    int v = (tid < NSB1) ? part[tid] : 0;
    s[tid] = v;
    __syncthreads();
    for (int off = 1; off < 1024; off <<= 1) {
        int t = (tid >= off) ? s[tid - off] : 0;
        __syncthreads();
        s[tid] += t;
        __syncthreads();
    }
    if (tid < NSB1) part[tid] = s[tid] - v;
}

__global__ __launch_bounds__(256) void k_scanC(int* __restrict__ data,
                                               const int* __restrict__ part) {
    int i = blockIdx.x * 256 + threadIdx.x;
    if (i < SCAN_N) data[i] += part[blockIdx.x];
}

// rec = { src | nl<<24, half2(ea0,ea1), half(ea2) }  — 1024 threads/block
__global__ __launch_bounds__(1024) void k_part_scatter(const int* __restrict__ ei,
                                                       const float* __restrict__ ea,
                                                       const int* __restrict__ counts,
                                                       uint3* __restrict__ tmp) {
    __shared__ int sbase[NBKT];
    __shared__ int scnt[NBKT];
    for (int i = threadIdx.x; i < NBKT; i += 1024) {
        sbase[i] = counts[i * NPBLK + blockIdx.x];
        scnt[i] = 0;
    }
    __syncthreads();
    int base = blockIdx.x * EPB;
#pragma unroll
    for (int k = 0; k < EPB / 1024; ++k) {
        int e = base + k * 1024 + threadIdx.x;
        if (e >= NE) continue;
        int dst = ei[NE + e];
        int bkt = dst >> 8;
        int nl = dst & 255;
        int r = atomicAdd(&scnt[bkt], 1);
        int src = ei[e];
        __half2 p01 = __floats2half2_rn(ea[e * 3 + 0], ea[e * 3 + 1]);
        __half p2 = __float2half_rn(ea[e * 3 + 2]);
        uint3 rec;
        rec.x = (uint)(src | (nl << 24));
        rec.y = *reinterpret_cast<const uint*>(&p01);
        rec.z = (uint)__half_as_ushort(p2);
        tmp[sbase[bkt] + r] = rec;
    }
}

// per-bucket LDS counting sort -> exact node-sorted recs2 + row_off
__global__ __launch_bounds__(512) void k_bucket_sort(const int* __restrict__ counts,
                                                     const uint3* __restrict__ tmp,
                                                     uint3* __restrict__ recs2,
                                                     int* __restrict__ row_off) {
    __shared__ int cnt[NPB];
    __shared__ int s[NPB];
    int tid = threadIdx.x;
    int b = blockIdx.x;
    int boff = counts[b * NPBLK];
    int bend = (b == NBKT - 1) ? NE : counts[(b + 1) * NPBLK];
    if (tid < NPB) cnt[tid] = 0;
    __syncthreads();
    for (int i = boff + tid; i < bend; i += 512)
        atomicAdd(&cnt[(tmp[i].x >> 24) & 255], 1);
    __syncthreads();
    int v = (tid < NPB) ? cnt[tid] : 0;
    if (tid < NPB) s[tid] = v;
    __syncthreads();
    for (int off = 1; off < 256; off <<= 1) {
        int t = (tid >= off && tid < NPB) ? s[tid - off] : 0;
        __syncthreads();
        if (tid < NPB) s[tid] += t;
        __syncthreads();
    }
    if (tid < NPB) {
        int excl = s[tid] - v;
        int n = b * NPB + tid;
        if (n < NN) row_off[n] = boff + excl;
        cnt[tid] = excl;  // becomes fill counter
    }
    if (b == NBKT - 1 && tid == 0) row_off[NN] = NE;
    __syncthreads();
    for (int i = boff + tid; i < bend; i += 512) {
        uint3 r = tmp[i];
        int nl = (r.x >> 24) & 255;
        int p = atomicAdd(&cnt[nl], 1);
        recs2[boff + p] = r;
    }
}

// shared helper: per-block BN affine preamble into LDS (sc,sh per channel)
__device__ __forceinline__ void bn_preamble(float* ssc, float* ssh, int apply,
                                            const float* in_stats,
                                            const float* in_g, const float* in_b) {
    if (threadIdx.x < 32) {
        float s = 1.f, t = 0.f;
        if (apply) {
            int cc = threadIdx.x;
            float mu = in_stats[cc] * (1.0f / NN);
            float var = in_stats[32 + cc] * (1.0f / NN) - mu * mu;
            s = in_g[cc] * rsqrtf(var + 1e-5f);
            t = in_b[cc] - mu * s;
        }
        ssc[threadIdx.x] = s;
        ssh[threadIdx.x] = t;
    }
}

// ---------------- exact-CSR gather aggregation: 8 thr/node, 8B fp16 z gathers.
// Applies h = APPLY ? relu(z*sc+sh) : z on the fly, and ADDS OWN NODE's h so
// the output zb holds the complete z0 = h[n] + sum_msgs (mlp reads only zb).
template <int APPLY>
__global__ __launch_bounds__(256) void k_aggregate(const int* __restrict__ row_off,
                                                   const uint3* __restrict__ recs,
                                                   const float* __restrict__ ew,
                                                   const float* __restrict__ eb,
                                                   const __half* __restrict__ h16,
                                                   const float* __restrict__ in_stats,
                                                   const float* __restrict__ in_g,
                                                   const float* __restrict__ in_b,
                                                   float* __restrict__ agg) {
    __shared__ float sw[96];
    __shared__ float sb[32];
    __shared__ float ssc[32], ssh[32];
    if (threadIdx.x < 96) sw[threadIdx.x] = ew[threadIdx.x];
    if (threadIdx.x < 32) sb[threadIdx.x] = eb[threadIdx.x];
    bn_preamble(ssc, ssh, APPLY, in_stats, in_g, in_b);
    __syncthreads();
    int t = blockIdx.x * 256 + threadIdx.x;
    int n = t >> 3;
    if (n >= NN) return;
    int c = (t & 7) * 4;  // 4 channels per thread
    float w0[4], w1[4], w2[4], bb[4], acc[4], sc4[4], sh4[4];
#pragma unroll
    for (int j = 0; j < 4; ++j) {
        w0[j] = sw[c + j];
        w1[j] = sw[32 + c + j];
        w2[j] = sw[64 + c + j];
        bb[j] = sb[c + j];
        sc4[j] = ssc[c + j];
        sh4[j] = ssh[c + j];
        acc[j] = 0.f;
    }
    int s0 = row_off[n], s1 = row_off[n + 1];
    int i = s0;
    for (; i + 2 <= s1; i += 2) {
        uint3 r0 = recs[i];
        uint3 r1 = recs[i + 1];
        int src0 = r0.x & 0x00FFFFFF;
        int src1 = r1.x & 0x00FFFFFF;
        uint2 ha = *(const uint2*)(h16 + (size_t)src0 * 32 + c);
        uint2 hb = *(const uint2*)(h16 + (size_t)src1 * 32 + c);
        float2 e01a = __half22float2(*reinterpret_cast<const __half2*>(&r0.y));
        float e2a = __half2float(__ushort_as_half((unsigned short)(r0.z & 0xFFFF)));
        float2 e01b = __half22float2(*reinterpret_cast<const __half2*>(&r1.y));
        float e2b = __half2float(__ushort_as_half((unsigned short)(r1.z & 0xFFFF)));
        float fa[4], fb[4];
        {
            float2 t0 = __half22float2(*reinterpret_cast<const __half2*>(&ha.x));
            float2 t1 = __half22float2(*reinterpret_cast<const __half2*>(&ha.y));
            fa[0] = t0.x; fa[1] = t0.y; fa[2] = t1.x; fa[3] = t1.y;
            float2 u0 = __half22float2(*reinterpret_cast<const __half2*>(&hb.x));
            float2 u1 = __half22float2(*reinterpret_cast<const __half2*>(&hb.y));
            fb[0] = u0.x; fb[1] = u0.y; fb[2] = u1.x; fb[3] = u1.y;
        }
#pragma unroll
        for (int j = 0; j < 4; ++j) {
            float va = fa[j], vb = fb[j];
            if (APPLY) {
                va = fmaxf(va * sc4[j] + sh4[j], 0.f);
                vb = fmaxf(vb * sc4[j] + sh4[j], 0.f);
            }
            float ma = va + bb[j] + e01a.x * w0[j] + e01a.y * w1[j] + e2a * w2[j];
            float mb = vb + bb[j] + e01b.x * w0[j] + e01b.y * w1[j] + e2b * w2[j];
            acc[j] += fmaxf(ma, 0.f) + fmaxf(mb, 0.f);
        }
    }
    if (i < s1) {
        uint3 r0 = recs[i];
        int src0 = r0.x & 0x00FFFFFF;
        uint2 ha = *(const uint2*)(h16 + (size_t)src0 * 32 + c);
        float2 e01a = __half22float2(*reinterpret_cast<const __half2*>(&r0.y));
        float e2a = __half2float(__ushort_as_half((unsigned short)(r0.z & 0xFFFF)));
        float2 t0 = __half22float2(*reinterpret_cast<const __half2*>(&ha.x));
        float2 t1 = __half22float2(*reinterpret_cast<const __half2*>(&ha.y));
        float fa[4] = {t0.x, t0.y, t1.x, t1.y};
#pragma unroll
        for (int j = 0; j < 4; ++j) {
            float va = fa[j];
            if (APPLY) va = fmaxf(va * sc4[j] + sh4[j], 0.f);
            float ma = va + bb[j] + e01a.x * w0[j] + e01a.y * w1[j] + e2a * w2[j];
            acc[j] += fmaxf(ma, 0.f);
        }
    }
    // add own node's h (affine) so zb = complete z0 = h[n] + agg
    {
        uint2 hn = *(const uint2*)(h16 + (size_t)n * 32 + c);
        float2 t0 = __half22float2(*reinterpret_cast<const __half2*>(&hn.x));
        float2 t1 = __half22float2(*reinterpret_cast<const __half2*>(&hn.y));
        float fn[4] = {t0.x, t0.y, t1.x, t1.y};
#pragma unroll
        for (int j = 0; j < 4; ++j) {
            float vn = fn[j];
            if (APPLY) vn = fmaxf(vn * sc4[j] + sh4[j], 0.f);
            acc[j] += vn;
        }
    }
    *(float4*)(agg + (size_t)n * 32 + c) = make_float4(acc[0], acc[1], acc[2], acc[3]);
}

// ---------------- fallback atomic scatter (only if ws too small)
__global__ __launch_bounds__(256) void k_edge_scatter(const int* __restrict__ ei,
                                                      const float* __restrict__ ea,
                                                      const float* __restrict__ ew,
                                                      const float* __restrict__ eb,
                                                      const __half* __restrict__ h16,
                                                      const float* __restrict__ in_stats,
                                                      const float* __restrict__ in_g,
                                                      const float* __restrict__ in_b,
                                                      int apply,
                                                      float* __restrict__ agg) {
    __shared__ float sw[96];
    __shared__ float sb[32];
    __shared__ float ssc[32], ssh[32];
    if (threadIdx.x < 96) sw[threadIdx.x] = ew[threadIdx.x];
    if (threadIdx.x < 32) sb[threadIdx.x] = eb[threadIdx.x];
    bn_preamble(ssc, ssh, apply, in_stats, in_g, in_b);
    __syncthreads();
    int t = blockIdx.x * 256 + threadIdx.x;
    int edge = t >> 3;
    if (edge >= NE) return;
    int c = (t & 7) * 4;
    int src = ei[edge];
    int dst = ei[NE + edge];
    float a0 = ea[edge * 3 + 0];
    float a1 = ea[edge * 3 + 1];
    float a2 = ea[edge * 3 + 2];
    float4 hs = h16_load4(h16 + (size_t)src * 32 + c);
    if (apply) {
        hs.x = fmaxf(hs.x * ssc[c + 0] + ssh[c + 0], 0.f);
        hs.y = fmaxf(hs.y * ssc[c + 1] + ssh[c + 1], 0.f);
        hs.z = fmaxf(hs.z * ssc[c + 2] + ssh[c + 2], 0.f);
        hs.w = fmaxf(hs.w * ssc[c + 3] + ssh[c + 3], 0.f);
    }
    float m0 = hs.x + sb[c + 0] + a0 * sw[c + 0] + a1 * sw[32 + c + 0] + a2 * sw[64 + c + 0];
    float m1 = hs.y + sb[c + 1] + a0 * sw[c + 1] + a1 * sw[32 + c + 1] + a2 * sw[64 + c + 1];
    float m2 = hs.z + sb[c + 2] + a0 * sw[c + 2] + a1 * sw[32 + c + 2] + a2 * sw[64 + c + 2];
    float m3 = hs.w + sb[c + 3] + a0 * sw[c + 3] + a1 * sw[32 + c + 3] + a2 * sw[64 + c + 3];
    float* o = agg + (size_t)dst * 32 + c;
    fadd(o + 0, fmaxf(m0, 0.f));
    fadd(o + 1, fmaxf(m1, 0.f));
    fadd(o + 2, fmaxf(m2, 0.f));
    fadd(o + 3, fmaxf(m3, 0.f));
}

// ---------------- own-node add for fallback path (zb += h_affine[n])
__global__ __launch_bounds__(256) void k_self_add(const __half* __restrict__ h16,
                                                  const float* __restrict__ in_stats,
                                                  const float* __restrict__ in_g,
                                                  const float* __restrict__ in_b,
                                                  int apply,
                                                  float* __restrict__ agg) {
    __shared__ float ssc[32], ssh[32];
    bn_preamble(ssc, ssh, apply, in_stats, in_g, in_b);
    __syncthreads();
    int i = blockIdx.x * 256 + threadIdx.x;
    if (i >= NN * 8) return;
    int c = (i & 7) * 4;
    float4 v = h16_load4(h16 + (size_t)i * 4);
    if (apply) {
        v.x = fmaxf(v.x * ssc[c + 0] + ssh[c + 0], 0.f);
        v.y = fmaxf(v.y * ssc[c + 1] + ssh[c + 1], 0.f);
        v.z = fmaxf(v.z * ssc[c + 2] + ssh[c + 2], 0.f);
        v.w = fmaxf(v.w * ssc[c + 3] + ssh[c + 3], 0.f);
    }
    float4 a = *(const float4*)(agg + (size_t)i * 4);
    *(float4*)(agg + (size_t)i * 4) = make_float4(a.x + v.x, a.y + v.y, a.z + v.z, a.w + v.w);
}

// ---------------- node MLP + fused BN stats; 2 WAVES/64-node group.
// Wave pair p (waves 2p, 2p+1) handles 64 nodes; wave 2p+half computes hidden
// units [19h, 19h+19). half is WAVE-uniform (readfirstlane) so weight loads
// stay SCALAR (s_load). Partials combine via padded LDS; half-0 wave stores
// the row and contributes BN stats.
__global__ __launch_bounds__(256) void k_mlp_stats(__half* __restrict__ hio,
                                                   const float* __restrict__ agg,
                                                   const uint* __restrict__ w1h_u,
                                                   const float* __restrict__ b1p,
                                                   const uint* __restrict__ w2p_u,
                                                   const float* __restrict__ b2,
                                                   float* __restrict__ stats) {
    __shared__ float lacc[2][64][33];  // padded: conflict-free pair combine
    __shared__ float ls[2][64];
    const h2* w1h = reinterpret_cast<const h2*>(w1h_u);
    const h2* w2p = reinterpret_cast<const h2*>(w2p_u);
    int tid = threadIdx.x;
    int wave = tid >> 6, lane = tid & 63;
    int pairp = wave >> 1;
    int halfu = __builtin_amdgcn_readfirstlane(wave & 1);  // wave-uniform!
    int n = blockIdx.x * 128 + pairp * 64 + lane;
    bool valid = n < NN;
    h2 zp[16];
    float acc[32];
    if (valid) {
#pragma unroll
        for (int c = 0; c < 32; c += 4) {
            float4 av = *(const float4*)(agg + (size_t)n * 32 + c);
            zp[c / 2] = pk16(av.x, av.y);
            zp[c / 2 + 1] = pk16(av.z, av.w);
        }
    } else {
#pragma unroll
        for (int p = 0; p < 16; ++p) zp[p] = pk16(0.f, 0.f);
    }
#pragma unroll
    for (int k = 0; k < 32; ++k) acc[k] = halfu ? 0.f : b2[k];
    int jp0 = 19 * halfu;
    for (int jp = jp0; jp < jp0 + 19; ++jp) {
        float t0a = b1p[2 * jp], t0b = 0.f;
        float t1a = b1p[2 * jp + 1], t1b = 0.f;
        const h2* r0 = w1h + (2 * jp) * 16;
        const h2* r1 = w1h + (2 * jp + 1) * 16;
#pragma unroll
        for (int p = 0; p < 8; ++p) {
            t0a = fdot2(zp[2 * p], r0[2 * p], t0a);
            t0b = fdot2(zp[2 * p + 1], r0[2 * p + 1], t0b);
            t1a = fdot2(zp[2 * p], r1[2 * p], t1a);
            t1b = fdot2(zp[2 * p + 1], r1[2 * p + 1], t1b);
        }
        float t0 = fmaxf(t0a + t0b, 0.f);
        float t1 = fmaxf(t1a + t1b, 0.f);
        h2 tp = pk16(t0, t1);
        const h2* c2 = w2p + jp * 32;
#pragma unroll
        for (int k = 0; k < 32; ++k) acc[k] = fdot2(tp, c2[k], acc[k]);
    }
    // combine wave pair through LDS (half-1 writes, half-0 reads+adds)
    if (halfu) {
#pragma unroll
        for (int k = 0; k < 32; ++k) lacc[pairp][lane][k] = acc[k];
    }
    __syncthreads();
    if (!halfu) {
#pragma unroll
        for (int k = 0; k < 32; ++k) acc[k] += lacc[pairp][lane][k];
        if (valid) {
#pragma unroll
            for (int c = 0; c < 32; c += 4)
                h16_store4(hio + (size_t)n * 32 + c,
                           make_float4(acc[c], acc[c + 1], acc[c + 2], acc[c + 3]));
        } else {
#pragma unroll
            for (int k = 0; k < 32; ++k) acc[k] = 0.f;
        }
        // BN stats butterfly (half-0 waves only; each node counted once)
#pragma unroll
        for (int k = 0; k < 32; ++k) {
            float sv = acc[k];
            float qv = sv * sv;
#pragma unroll
            for (int off = 1; off < 64; off <<= 1) {
                sv += __shfl_xor(sv, off);
                qv += __shfl_xor(qv, off);
            }
            if (lane == 0) {
                ls[pairp][k] = sv;
                ls[pairp][32 + k] = qv;
            }
        }
    }
    __syncthreads();
    if (tid < 64)
        fadd(&stats[tid], ls[0][tid] + ls[1][tid]);
}

// ---------------- pool: batch sorted — affine+relu on the fly, flush per boundary
__global__ __launch_bounds__(256) void k_pool(const __half* __restrict__ h16,
                                              const int* __restrict__ batch,
                                              const float* __restrict__ in_stats,
                                              const float* __restrict__ in_g,
                                              const float* __restrict__ in_b,
                                              float* __restrict__ gsum,
                                              float* __restrict__ gcnt) {
    __shared__ float ssc[32], ssh[32];
    bn_preamble(ssc, ssh, 1, in_stats, in_g, in_b);
    __syncthreads();
    int gid = blockIdx.x * 256 + threadIdx.x;
    int nb = (gid >> 3) * 8;
    if (nb >= NN) return;
    int c = (gid & 7) * 4;
    bool lead = (gid & 7) == 0;
    float sc0 = ssc[c], sc1 = ssc[c + 1], sc2 = ssc[c + 2], sc3 = ssc[c + 3];
    float sh0 = ssh[c], sh1 = ssh[c + 1], sh2 = ssh[c + 2], sh3 = ssh[c + 3];
    float4 acc = make_float4(0.f, 0.f, 0.f, 0.f);
    float cnt = 0.f;
    int cur = batch[nb];
#pragma unroll
    for (int k = 0; k < 8; ++k) {
        int n = nb + k;
        if (n >= NN) break;
        int bg = batch[n];
        if (bg != cur) {
            float* o = gsum + (size_t)cur * 32 + c;
            fadd(o + 0, acc.x); fadd(o + 1, acc.y);
            fadd(o + 2, acc.z); fadd(o + 3, acc.w);
            if (lead) fadd(&gcnt[cur], cnt);
            acc = make_float4(0.f, 0.f, 0.f, 0.f);
            cnt = 0.f;
            cur = bg;
        }
        float4 v = h16_load4(h16 + (size_t)n * 32 + c);
        acc.x += fmaxf(v.x * sc0 + sh0, 0.f);
        acc.y += fmaxf(v.y * sc1 + sh1, 0.f);
        acc.z += fmaxf(v.z * sc2 + sh2, 0.f);
        acc.w += fmaxf(v.w * sc3 + sh3, 0.f);
        cnt += 1.f;
    }
    float* o = gsum + (size_t)cur * 32 + c;
    fadd(o + 0, acc.x); fadd(o + 1, acc.y);
    fadd(o + 2, acc.z); fadd(o + 3, acc.w);
    if (lead) fadd(&gcnt[cur], cnt);
}

__global__ __launch_bounds__(256) void k_head(const float* __restrict__ gsum,
                                              const float* __restrict__ gcnt,
                                              const float* __restrict__ l1w,
                                              const float* __restrict__ l1b,
                                              const float* __restrict__ l2w,
                                              const float* __restrict__ l2b,
                                              float* __restrict__ out) {
    __shared__ float s1[32 * 16], sb1[16], s2[16 * 2], sb2[2];
    for (int i = threadIdx.x; i < 512; i += 256) s1[i] = l1w[i];
    if (threadIdx.x < 16) sb1[threadIdx.x] = l1b[threadIdx.x];
    if (threadIdx.x < 32) s2[threadIdx.x] = l2w[threadIdx.x];
    if (threadIdx.x < 2) sb2[threadIdx.x] = l2b[threadIdx.x];
    __syncthreads();
    int gi = blockIdx.x * 256 + threadIdx.x;
    if (gi >= NG) return;
    float inv = 1.0f / fmaxf(gcnt[gi], 1.0f);
    float gm[32];
#pragma unroll
    for (int c = 0; c < 32; c += 4) {
        float4 v = *(const float4*)(gsum + (size_t)gi * 32 + c);
        gm[c + 0] = v.x * inv;
        gm[c + 1] = v.y * inv;
        gm[c + 2] = v.z * inv;
        gm[c + 3] = v.w * inv;
    }
    float a[16];
#pragma unroll
    for (int j = 0; j < 16; ++j) {
        float t = sb1[j];
#pragma unroll
        for (int c = 0; c < 32; ++c) t += gm[c] * s1[c * 16 + j];
        a[j] = fmaxf(t, 0.f);
    }
    float o0 = sb2[0], o1 = sb2[1];
#pragma unroll
    for (int j = 0; j < 16; ++j) {
        o0 += a[j] * s2[j * 2 + 0];
        o1 += a[j] * s2[j * 2 + 1];
    }
    out[gi * 2 + 0] = o0;
    out[gi * 2 + 1] = o1;
}

extern "C" void kernel_launch(void* const* d_in, const int* in_sizes, int n_in,
                              void* d_out, int out_size, void* d_ws, size_t ws_size,
                              hipStream_t stream) {
    const float* x = (const float*)d_in[0];
    const int* ei = (const int*)d_in[1];
    const float* ea = (const float*)d_in[2];
    const int* batch = (const int*)d_in[3];
    const float* node_w = (const float*)d_in[4];
    const float* node_b = (const float*)d_in[5];
    const float* edge_w = (const float*)d_in[6];
    const float* edge_b = (const float*)d_in[7];
    const float* w1 = (const float*)d_in[8];
    const float* b1 = (const float*)d_in[9];
    const float* w2 = (const float*)d_in[10];
    const float* b2 = (const float*)d_in[11];
    const float* bng = (const float*)d_in[12];
    const float* bnb = (const float*)d_in[13];
    const float* l1w = (const float*)d_in[14];
    const float* l1b = (const float*)d_in[15];
    const float* l2w = (const float*)d_in[16];
    const float* l2b = (const float*)d_in[17];
    float* out = (float*)d_out;

    // workspace layout (float units)
    float* base = (float*)d_ws;
    __half* h16 = (__half*)base;                   // NN*32 halves = 3.2M floats (z16)
    float* zb = base + 3200000;                    // NN*32 fp32 (z0; aliases tmp)
    float* gsum = zb + (size_t)NN * 32;            // NG*32
    float* gcnt = gsum + (size_t)NG * 32;          // NG
    float* stats = gcnt + NG;                      // 2*64 (per layer)
    uint* w1h = (uint*)(stats + 128);              // 2*76*16 = 2432
    uint* w2p = w1h + 2 * 76 * 16;                 // 2*38*32 = 2432
    float* b1p = (float*)(w2p + 2 * 38 * 32);      // 152
    int* counts = (int*)(b1p + 152);               // SCAN_PAD
    int* part = counts + SCAN_PAD;                 // 1024
    int* row_off = part + 1024;                    // NN+4
    uint3* recs2 = (uint3*)(row_off + NN + 4);     // NE*3 uints
    uint3* tmp = (uint3*)zb;                       // NE*3 = 6.0M <= 6.4M floats

    size_t need_f = 3200000 + (size_t)NN * 32 + (size_t)NG * 33 + 128 + 2432 + 2432 + 152 +
                    SCAN_PAD + 1024 + ((size_t)NN + 4) + (size_t)NE * 3;
    bool use_fast = ws_size >= need_f * 4;

    if (use_fast) {
        k_hist<<<NPBLK, 1024, 0, stream>>>(ei, counts);
        k_scanA<<<NSB1, 256, 0, stream>>>(counts, part);
        k_scanB<<<1, 1024, 0, stream>>>(part);
        k_scanC<<<NSB1, 256, 0, stream>>>(counts, part);
        k_part_scatter<<<NPBLK, 1024, 0, stream>>>(ei, ea, counts, tmp);
        k_bucket_sort<<<NBKT, 512, 0, stream>>>(counts, tmp, recs2, row_off);
    }
    k_prep<<<(2 * 76 * 16 + 2 * 38 * 32 + 2 * 76 + 255) / 256, 256, 0, stream>>>(
        w1, b1, w2, w1h, w2p, b1p);

    k_node_embed<<<(NN + 255) / 256, 256, 0, stream>>>(x, node_w, node_b, h16);

    (void)hipMemsetAsync(stats, 0, 128 * sizeof(float), stream);

    for (int l = 0; l < 2; ++l) {
        int apply = (l > 0) ? 1 : 0;
        const float* prev_stats = (l > 0) ? (stats + (l - 1) * 64) : stats;
        const float* ig = (l > 0) ? (bng + (l - 1) * 32) : bng;  // unused when apply=0
        const float* ib = (l > 0) ? (bnb + (l - 1) * 32) : bnb;
        if (use_fast) {
            if (apply)
                k_aggregate<1><<<(NN * 8 + 255) / 256, 256, 0, stream>>>(row_off, recs2,
                                                                         edge_w, edge_b, h16,
                                                                         prev_stats, ig, ib, zb);
            else
                k_aggregate<0><<<(NN * 8 + 255) / 256, 256, 0, stream>>>(row_off, recs2,
                                                                         edge_w, edge_b, h16,
                                                                         prev_stats, ig, ib, zb);
        } else {
            (void)hipMemsetAsync(zb, 0, (size_t)NN * 32 * sizeof(float), stream);
            k_edge_scatter<<<(NE * 8) / 256, 256, 0, stream>>>(ei, ea, edge_w, edge_b, h16,
                                                               prev_stats, ig, ib, apply, zb);
            k_self_add<<<(NN * 8 + 255) / 256, 256, 0, stream>>>(h16, prev_stats, ig, ib,
                                                                 apply, zb);
        }
        k_mlp_stats<<<(NN + 127) / 128, 256, 0, stream>>>(h16, zb, w1h + l * 76 * 16,
                                                          b1p + l * 76, w2p + l * 38 * 32,
                                                          b2 + l * 32, stats + l * 64);
    }

    (void)hipMemsetAsync(gsum, 0, (size_t)(NG * 33) * sizeof(float), stream);
    k_pool<<<(NN + 255) / 256, 256, 0, stream>>>(h16, batch, stats + 64, bng + 32, bnb + 32,
                                                 gsum, gcnt);
    k_head<<<(NG + 255) / 256, 256, 0, stream>>>(gsum, gcnt, l1w, l1b, l2w, l2b, out);
}

// Round 20
// 293.774 us; speedup vs baseline: 1.7775x; 1.0418x over previous
//
#include <hip/hip_runtime.h>
#include <hip/hip_fp16.h>

#define NN 200000
#define NE 2000000
#define NG 10000

#define NPB 256                       // nodes per bucket (dst>>8)
#define NBKT 782                      // ceil(NN/NPB)
#define EPB 8192                      // edges per partition block
#define NPBLK 245                     // ceil(NE/EPB)
#define SCAN_N (NBKT * NPBLK)         // 191,590
#define SCAN_PAD 191592
#define NSB1 ((SCAN_N + 255) / 256)   // 749

typedef __fp16 h2 __attribute__((ext_vector_type(2)));

__device__ __forceinline__ void fadd(float* p, float v) {
    unsafeAtomicAdd(p, v);  // HW global_atomic_add_f32
}

__device__ __forceinline__ float fdot2(h2 a, h2 b, float c) {
#if __has_builtin(__builtin_amdgcn_fdot2)
    return __builtin_amdgcn_fdot2(a, b, c, false);
#else
    return c + (float)a.x * (float)b.x + (float)a.y * (float)b.y;
#endif
}

__device__ __forceinline__ h2 pk16(float a, float b) {
#if __has_builtin(__builtin_amdgcn_cvt_pkrtz)
    return __builtin_amdgcn_cvt_pkrtz(a, b);
#else
    h2 r;
    r.x = (__fp16)a;
    r.y = (__fp16)b;
    return r;
#endif
}

__device__ __forceinline__ float4 h16_load4(const __half* p) {
    uint2 r = *reinterpret_cast<const uint2*>(p);
    __half2 a = *reinterpret_cast<__half2*>(&r.x);
    __half2 b = *reinterpret_cast<__half2*>(&r.y);
    float2 f0 = __half22float2(a);
    float2 f1 = __half22float2(b);
    return make_float4(f0.x, f0.y, f1.x, f1.y);
}

__device__ __forceinline__ void h16_store4(__half* p, float4 v) {
    h2 a = pk16(v.x, v.y);
    h2 b = pk16(v.z, v.w);
    uint2 r;
    r.x = *reinterpret_cast<uint*>(&a);
    r.y = *reinterpret_cast<uint*>(&b);
    *reinterpret_cast<uint2*>(p) = r;
}

// ---------------- node embedding: h16 = x @ node_w + node_b  [N,14]->[N,32] fp16
__global__ __launch_bounds__(256) void k_node_embed(const float* __restrict__ x,
                                                    const float* __restrict__ w,
                                                    const float* __restrict__ b,
                                                    __half* __restrict__ h16) {
    __shared__ float sw[14 * 32];
    __shared__ float sb[32];
    for (int i = threadIdx.x; i < 14 * 32; i += 256) sw[i] = w[i];
    if (threadIdx.x < 32) sb[threadIdx.x] = b[threadIdx.x];
    __syncthreads();
    int n = blockIdx.x * 256 + threadIdx.x;
    if (n >= NN) return;
    float xi[14];
#pragma unroll
    for (int k = 0; k < 14; ++k) xi[k] = x[n * 14 + k];
#pragma unroll
    for (int c = 0; c < 32; c += 4) {
        float4 acc = make_float4(sb[c], sb[c + 1], sb[c + 2], sb[c + 3]);
#pragma unroll
        for (int k = 0; k < 14; ++k) {
            float xv = xi[k];
            acc.x += xv * sw[k * 32 + c + 0];
            acc.y += xv * sw[k * 32 + c + 1];
            acc.z += xv * sw[k * 32 + c + 2];
            acc.w += xv * sw[k * 32 + c + 3];
        }
        h16_store4(h16 + (size_t)n * 32 + c, acc);
    }
}

// ---------------- weight prep (once): fp16-pack MLP weights, pad j to 76
__global__ __launch_bounds__(256) void k_prep(const float* __restrict__ w1,
                                              const float* __restrict__ b1,
                                              const float* __restrict__ w2,
                                              uint* __restrict__ w1h,
                                              uint* __restrict__ w2p,
                                              float* __restrict__ b1p) {
    int i = blockIdx.x * 256 + threadIdx.x;
    if (i < 2 * 76 * 16) {
        int l = i / (76 * 16), r = i % (76 * 16);
        int j = r / 16, p = r % 16;
        float a = (j < 75) ? w1[l * 2400 + (2 * p) * 75 + j] : 0.f;
        float b = (j < 75) ? w1[l * 2400 + (2 * p + 1) * 75 + j] : 0.f;
        uint lo = __half_as_ushort(__float2half_rn(a));
        uint hi = __half_as_ushort(__float2half_rn(b));
        w1h[i] = lo | (hi << 16);
        return;
    }
    int i2 = i - 2 * 76 * 16;
    if (i2 >= 0 && i2 < 2 * 38 * 32) {
        int l = i2 / (38 * 32), r = i2 % (38 * 32);
        int jp = r / 32, k = r % 32;
        float a = w2[l * 2400 + (2 * jp) * 32 + k];
        float b = (2 * jp + 1 < 75) ? w2[l * 2400 + (2 * jp + 1) * 32 + k] : 0.f;
        uint lo = __half_as_ushort(__float2half_rn(a));
        uint hi = __half_as_ushort(__float2half_rn(b));
        w2p[i2] = lo | (hi << 16);
        return;
    }
    int i3 = i2 - 2 * 38 * 32;
    if (i3 >= 0 && i3 < 2 * 76) {
        int l = i3 / 76, j = i3 % 76;
        b1p[i3] = (j < 75) ? b1[l * 75 + j] : 0.f;
    }
}

// ================= bucket partition + per-bucket sort (once per launch) =========
__global__ __launch_bounds__(1024) void k_hist(const int* __restrict__ ei,
                                               int* __restrict__ counts) {
    __shared__ int hist[NBKT];
    for (int i = threadIdx.x; i < NBKT; i += 1024) hist[i] = 0;
    __syncthreads();
    int base = blockIdx.x * EPB;
#pragma unroll
    for (int k = 0; k < EPB / 1024; ++k) {
        int e = base + k * 1024 + threadIdx.x;
        if (e < NE) atomicAdd(&hist[ei[NE + e] >> 8], 1);
    }
    __syncthreads();
    for (int b = threadIdx.x; b < NBKT; b += 1024)
        counts[b * NPBLK + blockIdx.x] = hist[b];
}

__global__ __launch_bounds__(256) void k_scanA(int* __restrict__ data,
                                               int* __restrict__ part) {
    __shared__ int s[256];
    int tid = threadIdx.x;
    int i = blockIdx.x * 256 + tid;
    int v = (i < SCAN_N) ? data[i] : 0;
    s[tid] = v;
    __syncthreads();
    for (int off = 1; off < 256; off <<= 1) {
        int t = (tid >= off) ? s[tid - off] : 0;
        __syncthreads();
        s[tid] += t;
        __syncthreads();
    }
    if (i < SCAN_N) data[i] = s[tid] - v;
    if (tid == 255) part[blockIdx.x] = s[255];
}

__global__ __launch_bounds__(1024) void k_scanB(int* __restrict__ part) {
    __shared__ int s[1024];
    int tid = threadIdx.x;
    int v = (tid < NSB1) ? part[tid] : 0;
    s[tid] = v;
    __syncthreads();
    for (int off = 1; off < 1024; off <<= 1) {
        int t = (tid >= off) ? s[tid - off] : 0;
        __syncthreads();
        s[tid] += t;
        __syncthreads();
    }
    if (tid < NSB1) part[tid] = s[tid] - v;
}

// rec = { src | nl<<24, half2(ea0,ea1), half(ea2) }  — 1024 threads/block
// scanC fused: global base = counts[idx] + part[idx>>8]
__global__ __launch_bounds__(1024) void k_part_scatter(const int* __restrict__ ei,
                                                       const float* __restrict__ ea,
                                                       const int* __restrict__ counts,
                                                       const int* __restrict__ part,
                                                       uint3* __restrict__ tmp) {
    __shared__ int sbase[NBKT];
    __shared__ int scnt[NBKT];
    for (int i = threadIdx.x; i < NBKT; i += 1024) {
        int idx = i * NPBLK + blockIdx.x;
        sbase[i] = counts[idx] + part[idx >> 8];
        scnt[i] = 0;
    }
    __syncthreads();
    int base = blockIdx.x * EPB;
#pragma unroll
    for (int k = 0; k < EPB / 1024; ++k) {
        int e = base + k * 1024 + threadIdx.x;
        if (e >= NE) continue;
        int dst = ei[NE + e];
        int bkt = dst >> 8;
        int nl = dst & 255;
        int r = atomicAdd(&scnt[bkt], 1);
        int src = ei[e];
        __half2 p01 = __floats2half2_rn(ea[e * 3 + 0], ea[e * 3 + 1]);
        __half p2 = __float2half_rn(ea[e * 3 + 2]);
        uint3 rec;
        rec.x = (uint)(src | (nl << 24));
        rec.y = *reinterpret_cast<const uint*>(&p01);
        rec.z = (uint)__half_as_ushort(p2);
        tmp[sbase[bkt] + r] = rec;
    }
}

// per-bucket LDS counting sort -> exact node-sorted recs2 + row_off
__global__ __launch_bounds__(512) void k_bucket_sort(const int* __restrict__ counts,
                                                     const int* __restrict__ part,
                                                     const uint3* __restrict__ tmp,
                                                     uint3* __restrict__ recs2,
                                                     int* __restrict__ row_off) {
    __shared__ int cnt[NPB];
    __shared__ int s[NPB];
    int tid = threadIdx.x;
    int b = blockIdx.x;
    int idx0 = b * NPBLK;
    int boff = counts[idx0] + part[idx0 >> 8];
    int bend;
    if (b == NBKT - 1) {
        bend = NE;
    } else {
        int idx1 = (b + 1) * NPBLK;
        bend = counts[idx1] + part[idx1 >> 8];
    }
    if (tid < NPB) cnt[tid] = 0;
    __syncthreads();
    for (int i = boff + tid; i < bend; i += 512)
        atomicAdd(&cnt[(tmp[i].x >> 24) & 255], 1);
    __syncthreads();
    int v = (tid < NPB) ? cnt[tid] : 0;
    if (tid < NPB) s[tid] = v;
    __syncthreads();
    for (int off = 1; off < 256; off <<= 1) {
        int t = (tid >= off && tid < NPB) ? s[tid - off] : 0;
        __syncthreads();
        if (tid < NPB) s[tid] += t;
        __syncthreads();
    }
    if (tid < NPB) {
        int excl = s[tid] - v;
        int n = b * NPB + tid;
        if (n < NN) row_off[n] = boff + excl;
        cnt[tid] = excl;  // becomes fill counter
    }
    if (b == NBKT - 1 && tid == 0) row_off[NN] = NE;
    __syncthreads();
    for (int i = boff + tid; i < bend; i += 512) {
        uint3 r = tmp[i];
        int nl = (r.x >> 24) & 255;
        int p = atomicAdd(&cnt[nl], 1);
        recs2[boff + p] = r;
    }
}

// shared helper: per-block BN affine preamble into LDS (sc,sh per channel)
__device__ __forceinline__ void bn_preamble(float* ssc, float* ssh, int apply,
                                            const float* in_stats,
                                            const float* in_g, const float* in_b) {
    if (threadIdx.x < 32) {
        float s = 1.f, t = 0.f;
        if (apply) {
            int cc = threadIdx.x;
            float mu = in_stats[cc] * (1.0f / NN);
            float var = in_stats[32 + cc] * (1.0f / NN) - mu * mu;
            s = in_g[cc] * rsqrtf(var + 1e-5f);
            t = in_b[cc] - mu * s;
        }
        ssc[threadIdx.x] = s;
        ssh[threadIdx.x] = t;
    }
}

// ---------------- exact-CSR gather aggregation: 8 thr/node, 8B fp16 z gathers.
// Applies h = APPLY ? relu(z*sc+sh) : z on the fly, and ADDS OWN NODE's h so
// the output zb holds the complete z0 = h[n] + sum_msgs (mlp reads only zb).
template <int APPLY>
__global__ __launch_bounds__(256) void k_aggregate(const int* __restrict__ row_off,
                                                   const uint3* __restrict__ recs,
                                                   const float* __restrict__ ew,
                                                   const float* __restrict__ eb,
                                                   const __half* __restrict__ h16,
                                                   const float* __restrict__ in_stats,
                                                   const float* __restrict__ in_g,
                                                   const float* __restrict__ in_b,
                                                   float* __restrict__ agg) {
    __shared__ float sw[96];
    __shared__ float sb[32];
    __shared__ float ssc[32], ssh[32];
    if (threadIdx.x < 96) sw[threadIdx.x] = ew[threadIdx.x];
    if (threadIdx.x < 32) sb[threadIdx.x] = eb[threadIdx.x];
    bn_preamble(ssc, ssh, APPLY, in_stats, in_g, in_b);
    __syncthreads();
    int t = blockIdx.x * 256 + threadIdx.x;
    int n = t >> 3;
    if (n >= NN) return;
    int c = (t & 7) * 4;  // 4 channels per thread
    float w0[4], w1[4], w2[4], bb[4], acc[4], sc4[4], sh4[4];
#pragma unroll
    for (int j = 0; j < 4; ++j) {
        w0[j] = sw[c + j];
        w1[j] = sw[32 + c + j];
        w2[j] = sw[64 + c + j];
        bb[j] = sb[c + j];
        sc4[j] = ssc[c + j];
        sh4[j] = ssh[c + j];
        acc[j] = 0.f;
    }
    int s0 = row_off[n], s1 = row_off[n + 1];
    int i = s0;
    for (; i + 2 <= s1; i += 2) {
        uint3 r0 = recs[i];
        uint3 r1 = recs[i + 1];
        int src0 = r0.x & 0x00FFFFFF;
        int src1 = r1.x & 0x00FFFFFF;
        uint2 ha = *(const uint2*)(h16 + (size_t)src0 * 32 + c);
        uint2 hb = *(const uint2*)(h16 + (size_t)src1 * 32 + c);
        float2 e01a = __half22float2(*reinterpret_cast<const __half2*>(&r0.y));
        float e2a = __half2float(__ushort_as_half((unsigned short)(r0.z & 0xFFFF)));
        float2 e01b = __half22float2(*reinterpret_cast<const __half2*>(&r1.y));
        float e2b = __half2float(__ushort_as_half((unsigned short)(r1.z & 0xFFFF)));
        float fa[4], fb[4];
        {
            float2 t0 = __half22float2(*reinterpret_cast<const __half2*>(&ha.x));
            float2 t1 = __half22float2(*reinterpret_cast<const __half2*>(&ha.y));
            fa[0] = t0.x; fa[1] = t0.y; fa[2] = t1.x; fa[3] = t1.y;
            float2 u0 = __half22float2(*reinterpret_cast<const __half2*>(&hb.x));
            float2 u1 = __half22float2(*reinterpret_cast<const __half2*>(&hb.y));
            fb[0] = u0.x; fb[1] = u0.y; fb[2] = u1.x; fb[3] = u1.y;
        }
#pragma unroll
        for (int j = 0; j < 4; ++j) {
            float va = fa[j], vb = fb[j];
            if (APPLY) {
                va = fmaxf(va * sc4[j] + sh4[j], 0.f);
                vb = fmaxf(vb * sc4[j] + sh4[j], 0.f);
            }
            float ma = va + bb[j] + e01a.x * w0[j] + e01a.y * w1[j] + e2a * w2[j];
            float mb = vb + bb[j] + e01b.x * w0[j] + e01b.y * w1[j] + e2b * w2[j];
            acc[j] += fmaxf(ma, 0.f) + fmaxf(mb, 0.f);
        }
    }
    if (i < s1) {
        uint3 r0 = recs[i];
        int src0 = r0.x & 0x00FFFFFF;
        uint2 ha = *(const uint2*)(h16 + (size_t)src0 * 32 + c);
        float2 e01a = __half22float2(*reinterpret_cast<const __half2*>(&r0.y));
        float e2a = __half2float(__ushort_as_half((unsigned short)(r0.z & 0xFFFF)));
        float2 t0 = __half22float2(*reinterpret_cast<const __half2*>(&ha.x));
        float2 t1 = __half22float2(*reinterpret_cast<const __half2*>(&ha.y));
        float fa[4] = {t0.x, t0.y, t1.x, t1.y};
#pragma unroll
        for (int j = 0; j < 4; ++j) {
            float va = fa[j];
            if (APPLY) va = fmaxf(va * sc4[j] + sh4[j], 0.f);
            float ma = va + bb[j] + e01a.x * w0[j] + e01a.y * w1[j] + e2a * w2[j];
            acc[j] += fmaxf(ma, 0.f);
        }
    }
    // add own node's h (affine) so zb = complete z0 = h[n] + agg
    {
        uint2 hn = *(const uint2*)(h16 + (size_t)n * 32 + c);
        float2 t0 = __half22float2(*reinterpret_cast<const __half2*>(&hn.x));
        float2 t1 = __half22float2(*reinterpret_cast<const __half2*>(&hn.y));
        float fn[4] = {t0.x, t0.y, t1.x, t1.y};
#pragma unroll
        for (int j = 0; j < 4; ++j) {
            float vn = fn[j];
            if (APPLY) vn = fmaxf(vn * sc4[j] + sh4[j], 0.f);
            acc[j] += vn;
        }
    }
    *(float4*)(agg + (size_t)n * 32 + c) = make_float4(acc[0], acc[1], acc[2], acc[3]);
}

// ---------------- fallback atomic scatter (only if ws too small)
__global__ __launch_bounds__(256) void k_edge_scatter(const int* __restrict__ ei,
                                                      const float* __restrict__ ea,
                                                      const float* __restrict__ ew,
                                                      const float* __restrict__ eb,
                                                      const __half* __restrict__ h16,
                                                      const float* __restrict__ in_stats,
                                                      const float* __restrict__ in_g,
                                                      const float* __restrict__ in_b,
                                                      int apply,
                                                      float* __restrict__ agg) {
    __shared__ float sw[96];
    __shared__ float sb[32];
    __shared__ float ssc[32], ssh[32];
    if (threadIdx.x < 96) sw[threadIdx.x] = ew[threadIdx.x];
    if (threadIdx.x < 32) sb[threadIdx.x] = eb[threadIdx.x];
    bn_preamble(ssc, ssh, apply, in_stats, in_g, in_b);
    __syncthreads();
    int t = blockIdx.x * 256 + threadIdx.x;
    int edge = t >> 3;
    if (edge >= NE) return;
    int c = (t & 7) * 4;
    int src = ei[edge];
    int dst = ei[NE + edge];
    float a0 = ea[edge * 3 + 0];
    float a1 = ea[edge * 3 + 1];
    float a2 = ea[edge * 3 + 2];
    float4 hs = h16_load4(h16 + (size_t)src * 32 + c);
    if (apply) {
        hs.x = fmaxf(hs.x * ssc[c + 0] + ssh[c + 0], 0.f);
        hs.y = fmaxf(hs.y * ssc[c + 1] + ssh[c + 1], 0.f);
        hs.z = fmaxf(hs.z * ssc[c + 2] + ssh[c + 2], 0.f);
        hs.w = fmaxf(hs.w * ssc[c + 3] + ssh[c + 3], 0.f);
    }
    float m0 = hs.x + sb[c + 0] + a0 * sw[c + 0] + a1 * sw[32 + c + 0] + a2 * sw[64 + c + 0];
    float m1 = hs.y + sb[c + 1] + a0 * sw[c + 1] + a1 * sw[32 + c + 1] + a2 * sw[64 + c + 1];
    float m2 = hs.z + sb[c + 2] + a0 * sw[c + 2] + a1 * sw[32 + c + 2] + a2 * sw[64 + c + 2];
    float m3 = hs.w + sb[c + 3] + a0 * sw[c + 3] + a1 * sw[32 + c + 3] + a2 * sw[64 + c + 3];
    float* o = agg + (size_t)dst * 32 + c;
    fadd(o + 0, fmaxf(m0, 0.f));
    fadd(o + 1, fmaxf(m1, 0.f));
    fadd(o + 2, fmaxf(m2, 0.f));
    fadd(o + 3, fmaxf(m3, 0.f));
}

// ---------------- own-node add for fallback path (zb += h_affine[n])
__global__ __launch_bounds__(256) void k_self_add(const __half* __restrict__ h16,
                                                  const float* __restrict__ in_stats,
                                                  const float* __restrict__ in_g,
                                                  const float* __restrict__ in_b,
                                                  int apply,
                                                  float* __restrict__ agg) {
    __shared__ float ssc[32], ssh[32];
    bn_preamble(ssc, ssh, apply, in_stats, in_g, in_b);
    __syncthreads();
    int i = blockIdx.x * 256 + threadIdx.x;
    if (i >= NN * 8) return;
    int c = (i & 7) * 4;
    float4 v = h16_load4(h16 + (size_t)i * 4);
    if (apply) {
        v.x = fmaxf(v.x * ssc[c + 0] + ssh[c + 0], 0.f);
        v.y = fmaxf(v.y * ssc[c + 1] + ssh[c + 1], 0.f);
        v.z = fmaxf(v.z * ssc[c + 2] + ssh[c + 2], 0.f);
        v.w = fmaxf(v.w * ssc[c + 3] + ssh[c + 3], 0.f);
    }
    float4 a = *(const float4*)(agg + (size_t)i * 4);
    *(float4*)(agg + (size_t)i * 4) = make_float4(a.x + v.x, a.y + v.y, a.z + v.z, a.w + v.w);
}

// ---------------- node MLP + fused BN stats; 1 thr/node; weights staged in LDS
// (ds_read returns IN ORDER -> compiler pipelines with counted lgkmcnt, unlike
// s_load which forces lgkmcnt(0) drains). Broadcast reads: no bank conflicts.
__global__ __launch_bounds__(256) void k_mlp_stats(__half* __restrict__ hio,
                                                   const float* __restrict__ agg,
                                                   const uint* __restrict__ w1h_u,
                                                   const float* __restrict__ b1p_g,
                                                   const uint* __restrict__ w2p_u,
                                                   const float* __restrict__ b2_g,
                                                   float* __restrict__ stats) {
    __shared__ float ls[4][64];
    __shared__ uint sw1[76 * 16];   // 1216
    __shared__ uint sw2[38 * 32];   // 1216
    __shared__ float sb1[76];
    __shared__ float sb2[32];
    int tid = threadIdx.x;
    for (int i = tid; i < 1216; i += 256) {
        sw1[i] = w1h_u[i];
        sw2[i] = w2p_u[i];
    }
    if (tid < 76) sb1[tid] = b1p_g[tid];
    if (tid < 32) sb2[tid] = b2_g[tid];
    __syncthreads();
    const h2* w1h = reinterpret_cast<const h2*>(sw1);
    const h2* w2p = reinterpret_cast<const h2*>(sw2);
    int n = blockIdx.x * 256 + tid;
    bool valid = n < NN;
    h2 zp[16];
    float acc[32];
    if (valid) {
#pragma unroll
        for (int c = 0; c < 32; c += 4) {
            float4 av = *(const float4*)(agg + (size_t)n * 32 + c);
            zp[c / 2] = pk16(av.x, av.y);
            zp[c / 2 + 1] = pk16(av.z, av.w);
        }
    } else {
#pragma unroll
        for (int p = 0; p < 16; ++p) zp[p] = pk16(0.f, 0.f);
    }
#pragma unroll
    for (int k = 0; k < 32; ++k) acc[k] = sb2[k];
    for (int jp = 0; jp < 38; ++jp) {
        float t0a = sb1[2 * jp], t0b = 0.f;
        float t1a = sb1[2 * jp + 1], t1b = 0.f;
        const h2* r0 = w1h + (2 * jp) * 16;
        const h2* r1 = w1h + (2 * jp + 1) * 16;
#pragma unroll
        for (int p = 0; p < 8; ++p) {
            t0a = fdot2(zp[2 * p], r0[2 * p], t0a);
            t0b = fdot2(zp[2 * p + 1], r0[2 * p + 1], t0b);
            t1a = fdot2(zp[2 * p], r1[2 * p], t1a);
            t1b = fdot2(zp[2 * p + 1], r1[2 * p + 1], t1b);
        }
        float t0 = fmaxf(t0a + t0b, 0.f);
        float t1 = fmaxf(t1a + t1b, 0.f);
        h2 tp = pk16(t0, t1);
        const h2* c2 = w2p + jp * 32;
#pragma unroll
        for (int k = 0; k < 32; ++k) acc[k] = fdot2(tp, c2[k], acc[k]);
    }
    if (valid) {
#pragma unroll
        for (int c = 0; c < 32; c += 4)
            h16_store4(hio + (size_t)n * 32 + c,
                       make_float4(acc[c], acc[c + 1], acc[c + 2], acc[c + 3]));
    } else {
#pragma unroll
        for (int k = 0; k < 32; ++k) acc[k] = 0.f;
    }
    // fused BN statistics: butterfly over 64 lanes, per channel
    int wave = tid >> 6, lane = tid & 63;
#pragma unroll
    for (int k = 0; k < 32; ++k) {
        float sv = acc[k];
        float qv = sv * sv;
#pragma unroll
        for (int off = 1; off < 64; off <<= 1) {
            sv += __shfl_xor(sv, off);
            qv += __shfl_xor(qv, off);
        }
        if (lane == 0) {
            ls[wave][k] = sv;
            ls[wave][32 + k] = qv;
        }
    }
    __syncthreads();
    if (tid < 64)
        fadd(&stats[tid], ls[0][tid] + ls[1][tid] + ls[2][tid] + ls[3][tid]);
}

// ---------------- pool: batch sorted — affine+relu on the fly, flush per boundary
__global__ __launch_bounds__(256) void k_pool(const __half* __restrict__ h16,
                                              const int* __restrict__ batch,
                                              const float* __restrict__ in_stats,
                                              const float* __restrict__ in_g,
                                              const float* __restrict__ in_b,
                                              float* __restrict__ gsum,
                                              float* __restrict__ gcnt) {
    __shared__ float ssc[32], ssh[32];
    bn_preamble(ssc, ssh, 1, in_stats, in_g, in_b);
    __syncthreads();
    int gid = blockIdx.x * 256 + threadIdx.x;
    int nb = (gid >> 3) * 8;
    if (nb >= NN) return;
    int c = (gid & 7) * 4;
    bool lead = (gid & 7) == 0;
    float sc0 = ssc[c], sc1 = ssc[c + 1], sc2 = ssc[c + 2], sc3 = ssc[c + 3];
    float sh0 = ssh[c], sh1 = ssh[c + 1], sh2 = ssh[c + 2], sh3 = ssh[c + 3];
    float4 acc = make_float4(0.f, 0.f, 0.f, 0.f);
    float cnt = 0.f;
    int cur = batch[nb];
#pragma unroll
    for (int k = 0; k < 8; ++k) {
        int n = nb + k;
        if (n >= NN) break;
        int bg = batch[n];
        if (bg != cur) {
            float* o = gsum + (size_t)cur * 32 + c;
            fadd(o + 0, acc.x); fadd(o + 1, acc.y);
            fadd(o + 2, acc.z); fadd(o + 3, acc.w);
            if (lead) fadd(&gcnt[cur], cnt);
            acc = make_float4(0.f, 0.f, 0.f, 0.f);
            cnt = 0.f;
            cur = bg;
        }
        float4 v = h16_load4(h16 + (size_t)n * 32 + c);
        acc.x += fmaxf(v.x * sc0 + sh0, 0.f);
        acc.y += fmaxf(v.y * sc1 + sh1, 0.f);
        acc.z += fmaxf(v.z * sc2 + sh2, 0.f);
        acc.w += fmaxf(v.w * sc3 + sh3, 0.f);
        cnt += 1.f;
    }
    float* o = gsum + (size_t)cur * 32 + c;
    fadd(o + 0, acc.x); fadd(o + 1, acc.y);
    fadd(o + 2, acc.z); fadd(o + 3, acc.w);
    if (lead) fadd(&gcnt[cur], cnt);
}

__global__ __launch_bounds__(256) void k_head(const float* __restrict__ gsum,
                                              const float* __restrict__ gcnt,
                                              const float* __restrict__ l1w,
                                              const float* __restrict__ l1b,
                                              const float* __restrict__ l2w,
                                              const float* __restrict__ l2b,
                                              float* __restrict__ out) {
    __shared__ float s1[32 * 16], sb1[16], s2[16 * 2], sb2[2];
    for (int i = threadIdx.x; i < 512; i += 256) s1[i] = l1w[i];
    if (threadIdx.x < 16) sb1[threadIdx.x] = l1b[threadIdx.x];
    if (threadIdx.x < 32) s2[threadIdx.x] = l2w[threadIdx.x];
    if (threadIdx.x < 2) sb2[threadIdx.x] = l2b[threadIdx.x];
    __syncthreads();
    int gi = blockIdx.x * 256 + threadIdx.x;
    if (gi >= NG) return;
    float inv = 1.0f / fmaxf(gcnt[gi], 1.0f);
    float gm[32];
#pragma unroll
    for (int c = 0; c < 32; c += 4) {
        float4 v = *(const float4*)(gsum + (size_t)gi * 32 + c);
        gm[c + 0] = v.x * inv;
        gm[c + 1] = v.y * inv;
        gm[c + 2] = v.z * inv;
        gm[c + 3] = v.w * inv;
    }
    float a[16];
#pragma unroll
    for (int j = 0; j < 16; ++j) {
        float t = sb1[j];
#pragma unroll
        for (int c = 0; c < 32; ++c) t += gm[c] * s1[c * 16 + j];
        a[j] = fmaxf(t, 0.f);
    }
    float o0 = sb2[0], o1 = sb2[1];
#pragma unroll
    for (int j = 0; j < 16; ++j) {
        o0 += a[j] * s2[j * 2 + 0];
        o1 += a[j] * s2[j * 2 + 1];
    }
    out[gi * 2 + 0] = o0;
    out[gi * 2 + 1] = o1;
}

extern "C" void kernel_launch(void* const* d_in, const int* in_sizes, int n_in,
                              void* d_out, int out_size, void* d_ws, size_t ws_size,
                              hipStream_t stream) {
    const float* x = (const float*)d_in[0];
    const int* ei = (const int*)d_in[1];
    const float* ea = (const float*)d_in[2];
    const int* batch = (const int*)d_in[3];
    const float* node_w = (const float*)d_in[4];
    const float* node_b = (const float*)d_in[5];
    const float* edge_w = (const float*)d_in[6];
    const float* edge_b = (const float*)d_in[7];
    const float* w1 = (const float*)d_in[8];
    const float* b1 = (const float*)d_in[9];
    const float* w2 = (const float*)d_in[10];
    const float* b2 = (const float*)d_in[11];
    const float* bng = (const float*)d_in[12];
    const float* bnb = (const float*)d_in[13];
    const float* l1w = (const float*)d_in[14];
    const float* l1b = (const float*)d_in[15];
    const float* l2w = (const float*)d_in[16];
    const float* l2b = (const float*)d_in[17];
    float* out = (float*)d_out;

    // workspace layout (float units)
    float* base = (float*)d_ws;
    __half* h16 = (__half*)base;                   // NN*32 halves = 3.2M floats (z16)
    float* zb = base + 3200000;                    // NN*32 fp32 (z0; aliases tmp)
    float* gsum = zb + (size_t)NN * 32;            // NG*32
    float* gcnt = gsum + (size_t)NG * 32;          // NG
    float* stats = gcnt + NG;                      // 2*64 (per layer)
    uint* w1h = (uint*)(stats + 128);              // 2*76*16 = 2432
    uint* w2p = w1h + 2 * 76 * 16;                 // 2*38*32 = 2432
    float* b1p = (float*)(w2p + 2 * 38 * 32);      // 152
    int* counts = (int*)(b1p + 152);               // SCAN_PAD
    int* part = counts + SCAN_PAD;                 // 1024
    int* row_off = part + 1024;                    // NN+4
    uint3* recs2 = (uint3*)(row_off + NN + 4);     // NE*3 uints
    uint3* tmp = (uint3*)zb;                       // NE*3 = 6.0M <= 6.4M floats

    size_t need_f = 3200000 + (size_t)NN * 32 + (size_t)NG * 33 + 128 + 2432 + 2432 + 152 +
                    SCAN_PAD + 1024 + ((size_t)NN + 4) + (size_t)NE * 3;
    bool use_fast = ws_size >= need_f * 4;

    if (use_fast) {
        k_hist<<<NPBLK, 1024, 0, stream>>>(ei, counts);
        k_scanA<<<NSB1, 256, 0, stream>>>(counts, part);
        k_scanB<<<1, 1024, 0, stream>>>(part);
        k_part_scatter<<<NPBLK, 1024, 0, stream>>>(ei, ea, counts, part, tmp);
        k_bucket_sort<<<NBKT, 512, 0, stream>>>(counts, part, tmp, recs2, row_off);
    }
    k_prep<<<(2 * 76 * 16 + 2 * 38 * 32 + 2 * 76 + 255) / 256, 256, 0, stream>>>(
        w1, b1, w2, w1h, w2p, b1p);

    k_node_embed<<<(NN + 255) / 256, 256, 0, stream>>>(x, node_w, node_b, h16);

    (void)hipMemsetAsync(stats, 0, 128 * sizeof(float), stream);

    for (int l = 0; l < 2; ++l) {
        int apply = (l > 0) ? 1 : 0;
        const float* prev_stats = (l > 0) ? (stats + (l - 1) * 64) : stats;
        const float* ig = (l > 0) ? (bng + (l - 1) * 32) : bng;  // unused when apply=0
        const float* ib = (l > 0) ? (bnb + (l - 1) * 32) : bnb;
        if (use_fast) {
            if (apply)
                k_aggregate<1><<<(NN * 8 + 255) / 256, 256, 0, stream>>>(row_off, recs2,
                                                                         edge_w, edge_b, h16,
                                                                         prev_stats, ig, ib, zb);
            else
                k_aggregate<0><<<(NN * 8 + 255) / 256, 256, 0, stream>>>(row_off, recs2,
                                                                         edge_w, edge_b, h16,
                                                                         prev_stats, ig, ib, zb);
        } else {
            (void)hipMemsetAsync(zb, 0, (size_t)NN * 32 * sizeof(float), stream);
            k_edge_scatter<<<(NE * 8) / 256, 256, 0, stream>>>(ei, ea, edge_w, edge_b, h16,
                                                               prev_stats, ig, ib, apply, zb);
            k_self_add<<<(NN * 8 + 255) / 256, 256, 0, stream>>>(h16, prev_stats, ig, ib,
                                                                 apply, zb);
        }
        k_mlp_stats<<<(NN + 255) / 256, 256, 0, stream>>>(h16, zb, w1h + l * 76 * 16,
                                                          b1p + l * 76, w2p + l * 38 * 32,
                                                          b2 + l * 32, stats + l * 64);
    }

    (void)hipMemsetAsync(gsum, 0, (size_t)(NG * 33) * sizeof(float), stream);
    k_pool<<<(NN + 255) / 256, 256, 0, stream>>>(h16, batch, stats + 64, bng + 32, bnb + 32,
                                                 gsum, gcnt);
    k_head<<<(NG + 255) / 256, 256, 0, stream>>>(gsum, gcnt, l1w, l1b, l2w, l2b, out);
}

// Round 21
// 285.643 us; speedup vs baseline: 1.8281x; 1.0285x over previous
//
#include <hip/hip_runtime.h>
#include <hip/hip_fp16.h>

#define NN 200000
#define NE 2000000
#define NG 10000

#define NPB 256                       // nodes per bucket (dst>>8)
#define NBKT 782                      // ceil(NN/NPB)
#define EPB 8192                      // edges per partition block
#define NPBLK 245                     // ceil(NE/EPB)
#define SCAN_N (NBKT * NPBLK)         // 191,590
#define SCAN_PAD 191592
#define NSB1 ((SCAN_N + 255) / 256)   // 749

typedef __fp16 h2 __attribute__((ext_vector_type(2)));

__device__ __forceinline__ void fadd(float* p, float v) {
    unsafeAtomicAdd(p, v);  // HW global_atomic_add_f32
}

__device__ __forceinline__ float fdot2(h2 a, h2 b, float c) {
#if __has_builtin(__builtin_amdgcn_fdot2)
    return __builtin_amdgcn_fdot2(a, b, c, false);
#else
    return c + (float)a.x * (float)b.x + (float)a.y * (float)b.y;
#endif
}

__device__ __forceinline__ h2 pk16(float a, float b) {
#if __has_builtin(__builtin_amdgcn_cvt_pkrtz)
    return __builtin_amdgcn_cvt_pkrtz(a, b);
#else
    h2 r;
    r.x = (__fp16)a;
    r.y = (__fp16)b;
    return r;
#endif
}

__device__ __forceinline__ float4 h16_load4(const __half* p) {
    uint2 r = *reinterpret_cast<const uint2*>(p);
    __half2 a = *reinterpret_cast<__half2*>(&r.x);
    __half2 b = *reinterpret_cast<__half2*>(&r.y);
    float2 f0 = __half22float2(a);
    float2 f1 = __half22float2(b);
    return make_float4(f0.x, f0.y, f1.x, f1.y);
}

__device__ __forceinline__ void h16_store4(__half* p, float4 v) {
    h2 a = pk16(v.x, v.y);
    h2 b = pk16(v.z, v.w);
    uint2 r;
    r.x = *reinterpret_cast<uint*>(&a);
    r.y = *reinterpret_cast<uint*>(&b);
    *reinterpret_cast<uint2*>(p) = r;
}

// ---------------- node embedding: h16 = x @ node_w + node_b  [N,14]->[N,32] fp16
__global__ __launch_bounds__(256) void k_node_embed(const float* __restrict__ x,
                                                    const float* __restrict__ w,
                                                    const float* __restrict__ b,
                                                    __half* __restrict__ h16) {
    __shared__ float sw[14 * 32];
    __shared__ float sb[32];
    for (int i = threadIdx.x; i < 14 * 32; i += 256) sw[i] = w[i];
    if (threadIdx.x < 32) sb[threadIdx.x] = b[threadIdx.x];
    __syncthreads();
    int n = blockIdx.x * 256 + threadIdx.x;
    if (n >= NN) return;
    float xi[14];
#pragma unroll
    for (int k = 0; k < 14; ++k) xi[k] = x[n * 14 + k];
#pragma unroll
    for (int c = 0; c < 32; c += 4) {
        float4 acc = make_float4(sb[c], sb[c + 1], sb[c + 2], sb[c + 3]);
#pragma unroll
        for (int k = 0; k < 14; ++k) {
            float xv = xi[k];
            acc.x += xv * sw[k * 32 + c + 0];
            acc.y += xv * sw[k * 32 + c + 1];
            acc.z += xv * sw[k * 32 + c + 2];
            acc.w += xv * sw[k * 32 + c + 3];
        }
        h16_store4(h16 + (size_t)n * 32 + c, acc);
    }
}

// ---------------- weight prep (once): fp16-pack MLP weights, pad j to 76
__global__ __launch_bounds__(256) void k_prep(const float* __restrict__ w1,
                                              const float* __restrict__ b1,
                                              const float* __restrict__ w2,
                                              uint* __restrict__ w1h,
                                              uint* __restrict__ w2p,
                                              float* __restrict__ b1p) {
    int i = blockIdx.x * 256 + threadIdx.x;
    if (i < 2 * 76 * 16) {
        int l = i / (76 * 16), r = i % (76 * 16);
        int j = r / 16, p = r % 16;
        float a = (j < 75) ? w1[l * 2400 + (2 * p) * 75 + j] : 0.f;
        float b = (j < 75) ? w1[l * 2400 + (2 * p + 1) * 75 + j] : 0.f;
        uint lo = __half_as_ushort(__float2half_rn(a));
        uint hi = __half_as_ushort(__float2half_rn(b));
        w1h[i] = lo | (hi << 16);
        return;
    }
    int i2 = i - 2 * 76 * 16;
    if (i2 >= 0 && i2 < 2 * 38 * 32) {
        int l = i2 / (38 * 32), r = i2 % (38 * 32);
        int jp = r / 32, k = r % 32;
        float a = w2[l * 2400 + (2 * jp) * 32 + k];
        float b = (2 * jp + 1 < 75) ? w2[l * 2400 + (2 * jp + 1) * 32 + k] : 0.f;
        uint lo = __half_as_ushort(__float2half_rn(a));
        uint hi = __half_as_ushort(__float2half_rn(b));
        w2p[i2] = lo | (hi << 16);
        return;
    }
    int i3 = i2 - 2 * 38 * 32;
    if (i3 >= 0 && i3 < 2 * 76) {
        int l = i3 / 76, j = i3 % 76;
        b1p[i3] = (j < 75) ? b1[l * 75 + j] : 0.f;
    }
}

// ================= bucket partition + per-bucket sort (once per launch) =========
__global__ __launch_bounds__(1024) void k_hist(const int* __restrict__ ei,
                                               int* __restrict__ counts) {
    __shared__ int hist[NBKT];
    for (int i = threadIdx.x; i < NBKT; i += 1024) hist[i] = 0;
    __syncthreads();
    int base = blockIdx.x * EPB;
#pragma unroll
    for (int k = 0; k < EPB / 1024; ++k) {
        int e = base + k * 1024 + threadIdx.x;
        if (e < NE) atomicAdd(&hist[ei[NE + e] >> 8], 1);
    }
    __syncthreads();
    for (int b = threadIdx.x; b < NBKT; b += 1024)
        counts[b * NPBLK + blockIdx.x] = hist[b];
}

__global__ __launch_bounds__(256) void k_scanA(int* __restrict__ data,
                                               int* __restrict__ part) {
    __shared__ int s[256];
    int tid = threadIdx.x;
    int i = blockIdx.x * 256 + tid;
    int v = (i < SCAN_N) ? data[i] : 0;
    s[tid] = v;
    __syncthreads();
    for (int off = 1; off < 256; off <<= 1) {
        int t = (tid >= off) ? s[tid - off] : 0;
        __syncthreads();
        s[tid] += t;
        __syncthreads();
    }
    if (i < SCAN_N) data[i] = s[tid] - v;
    if (tid == 255) part[blockIdx.x] = s[255];
}

__global__ __launch_bounds__(1024) void k_scanB(int* __restrict__ part) {
    __shared__ int s[1024];
    int tid = threadIdx.x;
    int v = (tid < NSB1) ? part[tid] : 0;
    s[tid] = v;
    __syncthreads();
    for (int off = 1; off < 1024; off <<= 1) {
        int t = (tid >= off) ? s[tid - off] : 0;
        __syncthreads();
        s[tid] += t;
        __syncthreads();
    }
    if (tid < NSB1) part[tid] = s[tid] - v;
}

// rec = { src | nl<<24, half2(ea0,ea1), half(ea2) }  — 1024 threads/block
// scanC fused: global base = counts[idx] + part[idx>>8]
__global__ __launch_bounds__(1024) void k_part_scatter(const int* __restrict__ ei,
                                                       const float* __restrict__ ea,
                                                       const int* __restrict__ counts,
                                                       const int* __restrict__ part,
                                                       uint3* __restrict__ tmp) {
    __shared__ int sbase[NBKT];
    __shared__ int scnt[NBKT];
    for (int i = threadIdx.x; i < NBKT; i += 1024) {
        int idx = i * NPBLK + blockIdx.x;
        sbase[i] = counts[idx] + part[idx >> 8];
        scnt[i] = 0;
    }
    __syncthreads();
    int base = blockIdx.x * EPB;
#pragma unroll
    for (int k = 0; k < EPB / 1024; ++k) {
        int e = base + k * 1024 + threadIdx.x;
        if (e >= NE) continue;
        int dst = ei[NE + e];
        int bkt = dst >> 8;
        int nl = dst & 255;
        int r = atomicAdd(&scnt[bkt], 1);
        int src = ei[e];
        __half2 p01 = __floats2half2_rn(ea[e * 3 + 0], ea[e * 3 + 1]);
        __half p2 = __float2half_rn(ea[e * 3 + 2]);
        uint3 rec;
        rec.x = (uint)(src | (nl << 24));
        rec.y = *reinterpret_cast<const uint*>(&p01);
        rec.z = (uint)__half_as_ushort(p2);
        tmp[sbase[bkt] + r] = rec;
    }
}

// per-bucket LDS counting sort -> exact node-sorted recs2 + row_off
__global__ __launch_bounds__(512) void k_bucket_sort(const int* __restrict__ counts,
                                                     const int* __restrict__ part,
                                                     const uint3* __restrict__ tmp,
                                                     uint3* __restrict__ recs2,
                                                     int* __restrict__ row_off) {
    __shared__ int cnt[NPB];
    __shared__ int s[NPB];
    int tid = threadIdx.x;
    int b = blockIdx.x;
    int idx0 = b * NPBLK;
    int boff = counts[idx0] + part[idx0 >> 8];
    int bend;
    if (b == NBKT - 1) {
        bend = NE;
    } else {
        int idx1 = (b + 1) * NPBLK;
        bend = counts[idx1] + part[idx1 >> 8];
    }
    if (tid < NPB) cnt[tid] = 0;
    __syncthreads();
    for (int i = boff + tid; i < bend; i += 512)
        atomicAdd(&cnt[(tmp[i].x >> 24) & 255], 1);
    __syncthreads();
    int v = (tid < NPB) ? cnt[tid] : 0;
    if (tid < NPB) s[tid] = v;
    __syncthreads();
    for (int off = 1; off < 256; off <<= 1) {
        int t = (tid >= off && tid < NPB) ? s[tid - off] : 0;
        __syncthreads();
        if (tid < NPB) s[tid] += t;
        __syncthreads();
    }
    if (tid < NPB) {
        int excl = s[tid] - v;
        int n = b * NPB + tid;
        if (n < NN) row_off[n] = boff + excl;
        cnt[tid] = excl;  // becomes fill counter
    }
    if (b == NBKT - 1 && tid == 0) row_off[NN] = NE;
    __syncthreads();
    for (int i = boff + tid; i < bend; i += 512) {
        uint3 r = tmp[i];
        int nl = (r.x >> 24) & 255;
        int p = atomicAdd(&cnt[nl], 1);
        recs2[boff + p] = r;
    }
}

// shared helper: per-block BN affine preamble into LDS (sc,sh per channel)
__device__ __forceinline__ void bn_preamble(float* ssc, float* ssh, int apply,
                                            const float* in_stats,
                                            const float* in_g, const float* in_b) {
    if (threadIdx.x < 32) {
        float s = 1.f, t = 0.f;
        if (apply) {
            int cc = threadIdx.x;
            float mu = in_stats[cc] * (1.0f / NN);
            float var = in_stats[32 + cc] * (1.0f / NN) - mu * mu;
            s = in_g[cc] * rsqrtf(var + 1e-5f);
            t = in_b[cc] - mu * s;
        }
        ssc[threadIdx.x] = s;
        ssh[threadIdx.x] = t;
    }
}

// ---------------- exact-CSR gather aggregation: 8 thr/node, 8B fp16 z gathers.
// Applies h = APPLY ? relu(z*sc+sh) : z on the fly, and ADDS OWN NODE's h so
// the output zb holds the complete z0 = h[n] + sum_msgs (mlp reads only zb).
template <int APPLY>
__global__ __launch_bounds__(256) void k_aggregate(const int* __restrict__ row_off,
                                                   const uint3* __restrict__ recs,
                                                   const float* __restrict__ ew,
                                                   const float* __restrict__ eb,
                                                   const __half* __restrict__ h16,
                                                   const float* __restrict__ in_stats,
                                                   const float* __restrict__ in_g,
                                                   const float* __restrict__ in_b,
                                                   float* __restrict__ agg) {
    __shared__ float sw[96];
    __shared__ float sb[32];
    __shared__ float ssc[32], ssh[32];
    if (threadIdx.x < 96) sw[threadIdx.x] = ew[threadIdx.x];
    if (threadIdx.x < 32) sb[threadIdx.x] = eb[threadIdx.x];
    bn_preamble(ssc, ssh, APPLY, in_stats, in_g, in_b);
    __syncthreads();
    int t = blockIdx.x * 256 + threadIdx.x;
    int n = t >> 3;
    if (n >= NN) return;
    int c = (t & 7) * 4;  // 4 channels per thread
    float w0[4], w1[4], w2[4], bb[4], acc[4], sc4[4], sh4[4];
#pragma unroll
    for (int j = 0; j < 4; ++j) {
        w0[j] = sw[c + j];
        w1[j] = sw[32 + c + j];
        w2[j] = sw[64 + c + j];
        bb[j] = sb[c + j];
        sc4[j] = ssc[c + j];
        sh4[j] = ssh[c + j];
        acc[j] = 0.f;
    }
    int s0 = row_off[n], s1 = row_off[n + 1];
    int i = s0;
    for (; i + 2 <= s1; i += 2) {
        uint3 r0 = recs[i];
        uint3 r1 = recs[i + 1];
        int src0 = r0.x & 0x00FFFFFF;
        int src1 = r1.x & 0x00FFFFFF;
        uint2 ha = *(const uint2*)(h16 + (size_t)src0 * 32 + c);
        uint2 hb = *(const uint2*)(h16 + (size_t)src1 * 32 + c);
        float2 e01a = __half22float2(*reinterpret_cast<const __half2*>(&r0.y));
        float e2a = __half2float(__ushort_as_half((unsigned short)(r0.z & 0xFFFF)));
        float2 e01b = __half22float2(*reinterpret_cast<const __half2*>(&r1.y));
        float e2b = __half2float(__ushort_as_half((unsigned short)(r1.z & 0xFFFF)));
        float fa[4], fb[4];
        {
            float2 t0 = __half22float2(*reinterpret_cast<const __half2*>(&ha.x));
            float2 t1 = __half22float2(*reinterpret_cast<const __half2*>(&ha.y));
            fa[0] = t0.x; fa[1] = t0.y; fa[2] = t1.x; fa[3] = t1.y;
            float2 u0 = __half22float2(*reinterpret_cast<const __half2*>(&hb.x));
            float2 u1 = __half22float2(*reinterpret_cast<const __half2*>(&hb.y));
            fb[0] = u0.x; fb[1] = u0.y; fb[2] = u1.x; fb[3] = u1.y;
        }
#pragma unroll
        for (int j = 0; j < 4; ++j) {
            float va = fa[j], vb = fb[j];
            if (APPLY) {
                va = fmaxf(va * sc4[j] + sh4[j], 0.f);
                vb = fmaxf(vb * sc4[j] + sh4[j], 0.f);
            }
            float ma = va + bb[j] + e01a.x * w0[j] + e01a.y * w1[j] + e2a * w2[j];
            float mb = vb + bb[j] + e01b.x * w0[j] + e01b.y * w1[j] + e2b * w2[j];
            acc[j] += fmaxf(ma, 0.f) + fmaxf(mb, 0.f);
        }
    }
    if (i < s1) {
        uint3 r0 = recs[i];
        int src0 = r0.x & 0x00FFFFFF;
        uint2 ha = *(const uint2*)(h16 + (size_t)src0 * 32 + c);
        float2 e01a = __half22float2(*reinterpret_cast<const __half2*>(&r0.y));
        float e2a = __half2float(__ushort_as_half((unsigned short)(r0.z & 0xFFFF)));
        float2 t0 = __half22float2(*reinterpret_cast<const __half2*>(&ha.x));
        float2 t1 = __half22float2(*reinterpret_cast<const __half2*>(&ha.y));
        float fa[4] = {t0.x, t0.y, t1.x, t1.y};
#pragma unroll
        for (int j = 0; j < 4; ++j) {
            float va = fa[j];
            if (APPLY) va = fmaxf(va * sc4[j] + sh4[j], 0.f);
            float ma = va + bb[j] + e01a.x * w0[j] + e01a.y * w1[j] + e2a * w2[j];
            acc[j] += fmaxf(ma, 0.f);
        }
    }
    // add own node's h (affine) so zb = complete z0 = h[n] + agg
    {
        uint2 hn = *(const uint2*)(h16 + (size_t)n * 32 + c);
        float2 t0 = __half22float2(*reinterpret_cast<const __half2*>(&hn.x));
        float2 t1 = __half22float2(*reinterpret_cast<const __half2*>(&hn.y));
        float fn[4] = {t0.x, t0.y, t1.x, t1.y};
#pragma unroll
        for (int j = 0; j < 4; ++j) {
            float vn = fn[j];
            if (APPLY) vn = fmaxf(vn * sc4[j] + sh4[j], 0.f);
            acc[j] += vn;
        }
    }
    *(float4*)(agg + (size_t)n * 32 + c) = make_float4(acc[0], acc[1], acc[2], acc[3]);
}

// ---------------- fallback atomic scatter (only if ws too small)
__global__ __launch_bounds__(256) void k_edge_scatter(const int* __restrict__ ei,
                                                      const float* __restrict__ ea,
                                                      const float* __restrict__ ew,
                                                      const float* __restrict__ eb,
                                                      const __half* __restrict__ h16,
                                                      const float* __restrict__ in_stats,
                                                      const float* __restrict__ in_g,
                                                      const float* __restrict__ in_b,
                                                      int apply,
                                                      float* __restrict__ agg) {
    __shared__ float sw[96];
    __shared__ float sb[32];
    __shared__ float ssc[32], ssh[32];
    if (threadIdx.x < 96) sw[threadIdx.x] = ew[threadIdx.x];
    if (threadIdx.x < 32) sb[threadIdx.x] = eb[threadIdx.x];
    bn_preamble(ssc, ssh, apply, in_stats, in_g, in_b);
    __syncthreads();
    int t = blockIdx.x * 256 + threadIdx.x;
    int edge = t >> 3;
    if (edge >= NE) return;
    int c = (t & 7) * 4;
    int src = ei[edge];
    int dst = ei[NE + edge];
    float a0 = ea[edge * 3 + 0];
    float a1 = ea[edge * 3 + 1];
    float a2 = ea[edge * 3 + 2];
    float4 hs = h16_load4(h16 + (size_t)src * 32 + c);
    if (apply) {
        hs.x = fmaxf(hs.x * ssc[c + 0] + ssh[c + 0], 0.f);
        hs.y = fmaxf(hs.y * ssc[c + 1] + ssh[c + 1], 0.f);
        hs.z = fmaxf(hs.z * ssc[c + 2] + ssh[c + 2], 0.f);
        hs.w = fmaxf(hs.w * ssc[c + 3] + ssh[c + 3], 0.f);
    }
    float m0 = hs.x + sb[c + 0] + a0 * sw[c + 0] + a1 * sw[32 + c + 0] + a2 * sw[64 + c + 0];
    float m1 = hs.y + sb[c + 1] + a0 * sw[c + 1] + a1 * sw[32 + c + 1] + a2 * sw[64 + c + 1];
    float m2 = hs.z + sb[c + 2] + a0 * sw[c + 2] + a1 * sw[32 + c + 2] + a2 * sw[64 + c + 2];
    float m3 = hs.w + sb[c + 3] + a0 * sw[c + 3] + a1 * sw[32 + c + 3] + a2 * sw[64 + c + 3];
    float* o = agg + (size_t)dst * 32 + c;
    fadd(o + 0, fmaxf(m0, 0.f));
    fadd(o + 1, fmaxf(m1, 0.f));
    fadd(o + 2, fmaxf(m2, 0.f));
    fadd(o + 3, fmaxf(m3, 0.f));
}

// ---------------- own-node add for fallback path (zb += h_affine[n])
__global__ __launch_bounds__(256) void k_self_add(const __half* __restrict__ h16,
                                                  const float* __restrict__ in_stats,
                                                  const float* __restrict__ in_g,
                                                  const float* __restrict__ in_b,
                                                  int apply,
                                                  float* __restrict__ agg) {
    __shared__ float ssc[32], ssh[32];
    bn_preamble(ssc, ssh, apply, in_stats, in_g, in_b);
    __syncthreads();
    int i = blockIdx.x * 256 + threadIdx.x;
    if (i >= NN * 8) return;
    int c = (i & 7) * 4;
    float4 v = h16_load4(h16 + (size_t)i * 4);
    if (apply) {
        v.x = fmaxf(v.x * ssc[c + 0] + ssh[c + 0], 0.f);
        v.y = fmaxf(v.y * ssc[c + 1] + ssh[c + 1], 0.f);
        v.z = fmaxf(v.z * ssc[c + 2] + ssh[c + 2], 0.f);
        v.w = fmaxf(v.w * ssc[c + 3] + ssh[c + 3], 0.f);
    }
    float4 a = *(const float4*)(agg + (size_t)i * 4);
    *(float4*)(agg + (size_t)i * 4) = make_float4(a.x + v.x, a.y + v.y, a.z + v.z, a.w + v.w);
}

// ---------------- node MLP + fused BN stats; 2 NODES/THREAD, weights in LDS.
// Each weight ds_read feeds 2 fdot2 -> LDS-pipe (the measured bottleneck) halves.
__global__ __launch_bounds__(256) void k_mlp_stats(__half* __restrict__ hio,
                                                   const float* __restrict__ agg,
                                                   const uint* __restrict__ w1h_u,
                                                   const float* __restrict__ b1p_g,
                                                   const uint* __restrict__ w2p_u,
                                                   const float* __restrict__ b2_g,
                                                   float* __restrict__ stats) {
    __shared__ float ls[4][64];
    __shared__ uint sw1[76 * 16];   // 1216 dwords
    __shared__ uint sw2[38 * 32];   // 1216 dwords
    __shared__ float sb1[76];
    __shared__ float sb2[32];
    int tid = threadIdx.x;
    for (int i = tid; i < 1216; i += 256) {
        sw1[i] = w1h_u[i];
        sw2[i] = w2p_u[i];
    }
    if (tid < 76) sb1[tid] = b1p_g[tid];
    if (tid < 32) sb2[tid] = b2_g[tid];
    __syncthreads();
    const h2* w1h = reinterpret_cast<const h2*>(sw1);
    const h2* w2p = reinterpret_cast<const h2*>(sw2);
    int n0 = blockIdx.x * 512 + tid;
    int n1 = n0 + 256;
    bool v0 = n0 < NN, v1 = n1 < NN;
    h2 zp0[16], zp1[16];
    float acc0[32], acc1[32];
    if (v0) {
#pragma unroll
        for (int c = 0; c < 32; c += 4) {
            float4 av = *(const float4*)(agg + (size_t)n0 * 32 + c);
            zp0[c / 2] = pk16(av.x, av.y);
            zp0[c / 2 + 1] = pk16(av.z, av.w);
        }
    } else {
#pragma unroll
        for (int p = 0; p < 16; ++p) zp0[p] = pk16(0.f, 0.f);
    }
    if (v1) {
#pragma unroll
        for (int c = 0; c < 32; c += 4) {
            float4 av = *(const float4*)(agg + (size_t)n1 * 32 + c);
            zp1[c / 2] = pk16(av.x, av.y);
            zp1[c / 2 + 1] = pk16(av.z, av.w);
        }
    } else {
#pragma unroll
        for (int p = 0; p < 16; ++p) zp1[p] = pk16(0.f, 0.f);
    }
#pragma unroll
    for (int k = 0; k < 32; ++k) {
        acc0[k] = sb2[k];
        acc1[k] = sb2[k];
    }
    for (int jp = 0; jp < 38; ++jp) {
        float b1a = sb1[2 * jp], b1b = sb1[2 * jp + 1];
        float s0a = b1a, s0b = 0.f, s1a = b1b, s1b = 0.f;      // node 0
        float u0a = b1a, u0b = 0.f, u1a = b1b, u1b = 0.f;      // node 1
        const h2* r0 = w1h + (2 * jp) * 16;
        const h2* r1 = w1h + (2 * jp + 1) * 16;
#pragma unroll
        for (int p = 0; p < 8; ++p) {
            h2 wa0 = r0[2 * p], wa1 = r0[2 * p + 1];
            h2 wb0 = r1[2 * p], wb1 = r1[2 * p + 1];
            s0a = fdot2(zp0[2 * p], wa0, s0a);
            s0b = fdot2(zp0[2 * p + 1], wa1, s0b);
            s1a = fdot2(zp0[2 * p], wb0, s1a);
            s1b = fdot2(zp0[2 * p + 1], wb1, s1b);
            u0a = fdot2(zp1[2 * p], wa0, u0a);
            u0b = fdot2(zp1[2 * p + 1], wa1, u0b);
            u1a = fdot2(zp1[2 * p], wb0, u1a);
            u1b = fdot2(zp1[2 * p + 1], wb1, u1b);
        }
        h2 tp0 = pk16(fmaxf(s0a + s0b, 0.f), fmaxf(s1a + s1b, 0.f));
        h2 tp1 = pk16(fmaxf(u0a + u0b, 0.f), fmaxf(u1a + u1b, 0.f));
        const h2* c2 = w2p + jp * 32;
#pragma unroll
        for (int k = 0; k < 32; ++k) {
            h2 wk = c2[k];
            acc0[k] = fdot2(tp0, wk, acc0[k]);
            acc1[k] = fdot2(tp1, wk, acc1[k]);
        }
    }
    if (v0) {
#pragma unroll
        for (int c = 0; c < 32; c += 4)
            h16_store4(hio + (size_t)n0 * 32 + c,
                       make_float4(acc0[c], acc0[c + 1], acc0[c + 2], acc0[c + 3]));
    } else {
#pragma unroll
        for (int k = 0; k < 32; ++k) acc0[k] = 0.f;
    }
    if (v1) {
#pragma unroll
        for (int c = 0; c < 32; c += 4)
            h16_store4(hio + (size_t)n1 * 32 + c,
                       make_float4(acc1[c], acc1[c + 1], acc1[c + 2], acc1[c + 3]));
    } else {
#pragma unroll
        for (int k = 0; k < 32; ++k) acc1[k] = 0.f;
    }
    // fused BN statistics over both nodes: butterfly over 64 lanes, per channel
    int wave = tid >> 6, lane = tid & 63;
#pragma unroll
    for (int k = 0; k < 32; ++k) {
        float sv = acc0[k] + acc1[k];
        float qv = acc0[k] * acc0[k] + acc1[k] * acc1[k];
#pragma unroll
        for (int off = 1; off < 64; off <<= 1) {
            sv += __shfl_xor(sv, off);
            qv += __shfl_xor(qv, off);
        }
        if (lane == 0) {
            ls[wave][k] = sv;
            ls[wave][32 + k] = qv;
        }
    }
    __syncthreads();
    if (tid < 64)
        fadd(&stats[tid], ls[0][tid] + ls[1][tid] + ls[2][tid] + ls[3][tid]);
}

// ---------------- pool: batch sorted — affine+relu on the fly, flush per boundary
__global__ __launch_bounds__(256) void k_pool(const __half* __restrict__ h16,
                                              const int* __restrict__ batch,
                                              const float* __restrict__ in_stats,
                                              const float* __restrict__ in_g,
                                              const float* __restrict__ in_b,
                                              float* __restrict__ gsum,
                                              float* __restrict__ gcnt) {
    __shared__ float ssc[32], ssh[32];
    bn_preamble(ssc, ssh, 1, in_stats, in_g, in_b);
    __syncthreads();
    int gid = blockIdx.x * 256 + threadIdx.x;
    int nb = (gid >> 3) * 8;
    if (nb >= NN) return;
    int c = (gid & 7) * 4;
    bool lead = (gid & 7) == 0;
    float sc0 = ssc[c], sc1 = ssc[c + 1], sc2 = ssc[c + 2], sc3 = ssc[c + 3];
    float sh0 = ssh[c], sh1 = ssh[c + 1], sh2 = ssh[c + 2], sh3 = ssh[c + 3];
    float4 acc = make_float4(0.f, 0.f, 0.f, 0.f);
    float cnt = 0.f;
    int cur = batch[nb];
#pragma unroll
    for (int k = 0; k < 8; ++k) {
        int n = nb + k;
        if (n >= NN) break;
        int bg = batch[n];
        if (bg != cur) {
            float* o = gsum + (size_t)cur * 32 + c;
            fadd(o + 0, acc.x); fadd(o + 1, acc.y);
            fadd(o + 2, acc.z); fadd(o + 3, acc.w);
            if (lead) fadd(&gcnt[cur], cnt);
            acc = make_float4(0.f, 0.f, 0.f, 0.f);
            cnt = 0.f;
            cur = bg;
        }
        float4 v = h16_load4(h16 + (size_t)n * 32 + c);
        acc.x += fmaxf(v.x * sc0 + sh0, 0.f);
        acc.y += fmaxf(v.y * sc1 + sh1, 0.f);
        acc.z += fmaxf(v.z * sc2 + sh2, 0.f);
        acc.w += fmaxf(v.w * sc3 + sh3, 0.f);
        cnt += 1.f;
    }
    float* o = gsum + (size_t)cur * 32 + c;
    fadd(o + 0, acc.x); fadd(o + 1, acc.y);
    fadd(o + 2, acc.z); fadd(o + 3, acc.w);
    if (lead) fadd(&gcnt[cur], cnt);
}

__global__ __launch_bounds__(256) void k_head(const float* __restrict__ gsum,
                                              const float* __restrict__ gcnt,
                                              const float* __restrict__ l1w,
                                              const float* __restrict__ l1b,
                                              const float* __restrict__ l2w,
                                              const float* __restrict__ l2b,
                                              float* __restrict__ out) {
    __shared__ float s1[32 * 16], sb1[16], s2[16 * 2], sb2[2];
    for (int i = threadIdx.x; i < 512; i += 256) s1[i] = l1w[i];
    if (threadIdx.x < 16) sb1[threadIdx.x] = l1b[threadIdx.x];
    if (threadIdx.x < 32) s2[threadIdx.x] = l2w[threadIdx.x];
    if (threadIdx.x < 2) sb2[threadIdx.x] = l2b[threadIdx.x];
    __syncthreads();
    int gi = blockIdx.x * 256 + threadIdx.x;
    if (gi >= NG) return;
    float inv = 1.0f / fmaxf(gcnt[gi], 1.0f);
    float gm[32];
#pragma unroll
    for (int c = 0; c < 32; c += 4) {
        float4 v = *(const float4*)(gsum + (size_t)gi * 32 + c);
        gm[c + 0] = v.x * inv;
        gm[c + 1] = v.y * inv;
        gm[c + 2] = v.z * inv;
        gm[c + 3] = v.w * inv;
    }
    float a[16];
#pragma unroll
    for (int j = 0; j < 16; ++j) {
        float t = sb1[j];
#pragma unroll
        for (int c = 0; c < 32; ++c) t += gm[c] * s1[c * 16 + j];
        a[j] = fmaxf(t, 0.f);
    }
    float o0 = sb2[0], o1 = sb2[1];
#pragma unroll
    for (int j = 0; j < 16; ++j) {
        o0 += a[j] * s2[j * 2 + 0];
        o1 += a[j] * s2[j * 2 + 1];
    }
    out[gi * 2 + 0] = o0;
    out[gi * 2 + 1] = o1;
}

extern "C" void kernel_launch(void* const* d_in, const int* in_sizes, int n_in,
                              void* d_out, int out_size, void* d_ws, size_t ws_size,
                              hipStream_t stream) {
    const float* x = (const float*)d_in[0];
    const int* ei = (const int*)d_in[1];
    const float* ea = (const float*)d_in[2];
    const int* batch = (const int*)d_in[3];
    const float* node_w = (const float*)d_in[4];
    const float* node_b = (const float*)d_in[5];
    const float* edge_w = (const float*)d_in[6];
    const float* edge_b = (const float*)d_in[7];
    const float* w1 = (const float*)d_in[8];
    const float* b1 = (const float*)d_in[9];
    const float* w2 = (const float*)d_in[10];
    const float* b2 = (const float*)d_in[11];
    const float* bng = (const float*)d_in[12];
    const float* bnb = (const float*)d_in[13];
    const float* l1w = (const float*)d_in[14];
    const float* l1b = (const float*)d_in[15];
    const float* l2w = (const float*)d_in[16];
    const float* l2b = (const float*)d_in[17];
    float* out = (float*)d_out;

    // workspace layout (float units)
    float* base = (float*)d_ws;
    __half* h16 = (__half*)base;                   // NN*32 halves = 3.2M floats (z16)
    float* zb = base + 3200000;                    // NN*32 fp32 (z0; aliases tmp)
    float* gsum = zb + (size_t)NN * 32;            // NG*32
    float* gcnt = gsum + (size_t)NG * 32;          // NG
    float* stats = gcnt + NG;                      // 2*64 (per layer)
    uint* w1h = (uint*)(stats + 128);              // 2*76*16 = 2432
    uint* w2p = w1h + 2 * 76 * 16;                 // 2*38*32 = 2432
    float* b1p = (float*)(w2p + 2 * 38 * 32);      // 152
    int* counts = (int*)(b1p + 152);               // SCAN_PAD
    int* part = counts + SCAN_PAD;                 // 1024
    int* row_off = part + 1024;                    // NN+4
    uint3* recs2 = (uint3*)(row_off + NN + 4);     // NE*3 uints
    uint3* tmp = (uint3*)zb;                       // NE*3 = 6.0M <= 6.4M floats

    size_t need_f = 3200000 + (size_t)NN * 32 + (size_t)NG * 33 + 128 + 2432 + 2432 + 152 +
                    SCAN_PAD + 1024 + ((size_t)NN + 4) + (size_t)NE * 3;
    bool use_fast = ws_size >= need_f * 4;

    if (use_fast) {
        k_hist<<<NPBLK, 1024, 0, stream>>>(ei, counts);
        k_scanA<<<NSB1, 256, 0, stream>>>(counts, part);
        k_scanB<<<1, 1024, 0, stream>>>(part);
        k_part_scatter<<<NPBLK, 1024, 0, stream>>>(ei, ea, counts, part, tmp);
        k_bucket_sort<<<NBKT, 512, 0, stream>>>(counts, part, tmp, recs2, row_off);
    }
    k_prep<<<(2 * 76 * 16 + 2 * 38 * 32 + 2 * 76 + 255) / 256, 256, 0, stream>>>(
        w1, b1, w2, w1h, w2p, b1p);

    k_node_embed<<<(NN + 255) / 256, 256, 0, stream>>>(x, node_w, node_b, h16);

    (void)hipMemsetAsync(stats, 0, 128 * sizeof(float), stream);

    for (int l = 0; l < 2; ++l) {
        int apply = (l > 0) ? 1 : 0;
        const float* prev_stats = (l > 0) ? (stats + (l - 1) * 64) : stats;
        const float* ig = (l > 0) ? (bng + (l - 1) * 32) : bng;  // unused when apply=0
        const float* ib = (l > 0) ? (bnb + (l - 1) * 32) : bnb;
        if (use_fast) {
            if (apply)
                k_aggregate<1><<<(NN * 8 + 255) / 256, 256, 0, stream>>>(row_off, recs2,
                                                                         edge_w, edge_b, h16,
                                                                         prev_stats, ig, ib, zb);
            else
                k_aggregate<0><<<(NN * 8 + 255) / 256, 256, 0, stream>>>(row_off, recs2,
                                                                         edge_w, edge_b, h16,
                                                                         prev_stats, ig, ib, zb);
        } else {
            (void)hipMemsetAsync(zb, 0, (size_t)NN * 32 * sizeof(float), stream);
            k_edge_scatter<<<(NE * 8) / 256, 256, 0, stream>>>(ei, ea, edge_w, edge_b, h16,
                                                               prev_stats, ig, ib, apply, zb);
            k_self_add<<<(NN * 8 + 255) / 256, 256, 0, stream>>>(h16, prev_stats, ig, ib,
                                                                 apply, zb);
        }
        k_mlp_stats<<<(NN + 511) / 512, 256, 0, stream>>>(h16, zb, w1h + l * 76 * 16,
                                                          b1p + l * 76, w2p + l * 38 * 32,
                                                          b2 + l * 32, stats + l * 64);
    }

    (void)hipMemsetAsync(gsum, 0, (size_t)(NG * 33) * sizeof(float), stream);
    k_pool<<<(NN + 255) / 256, 256, 0, stream>>>(h16, batch, stats + 64, bng + 32, bnb + 32,
                                                 gsum, gcnt);
    k_head<<<(NG + 255) / 256, 256, 0, stream>>>(gsum, gcnt, l1w, l1b, l2w, l2b, out);
}

// Round 22
// 284.405 us; speedup vs baseline: 1.8361x; 1.0044x over previous
//
#include <hip/hip_runtime.h>
#include <hip/hip_fp16.h>

#define NN 200000
#define NE 2000000
#define NG 10000

#define NPB 256                       // nodes per bucket (dst>>8)
#define NBKT 782                      // ceil(NN/NPB)
#define EPB 8192                      // edges per partition block
#define NPBLK 245                     // ceil(NE/EPB)
#define SCAN_N (NBKT * NPBLK)         // 191,590
#define SCAN_PAD 191592
#define NSB1 ((SCAN_N + 255) / 256)   // 749

typedef __fp16 h2 __attribute__((ext_vector_type(2)));

__device__ __forceinline__ void fadd(float* p, float v) {
    unsafeAtomicAdd(p, v);  // HW global_atomic_add_f32
}

__device__ __forceinline__ float fdot2(h2 a, h2 b, float c) {
#if __has_builtin(__builtin_amdgcn_fdot2)
    return __builtin_amdgcn_fdot2(a, b, c, false);
#else
    return c + (float)a.x * (float)b.x + (float)a.y * (float)b.y;
#endif
}

__device__ __forceinline__ h2 pk16(float a, float b) {
#if __has_builtin(__builtin_amdgcn_cvt_pkrtz)
    return __builtin_amdgcn_cvt_pkrtz(a, b);
#else
    h2 r;
    r.x = (__fp16)a;
    r.y = (__fp16)b;
    return r;
#endif
}

__device__ __forceinline__ float4 h16_load4(const __half* p) {
    uint2 r = *reinterpret_cast<const uint2*>(p);
    __half2 a = *reinterpret_cast<__half2*>(&r.x);
    __half2 b = *reinterpret_cast<__half2*>(&r.y);
    float2 f0 = __half22float2(a);
    float2 f1 = __half22float2(b);
    return make_float4(f0.x, f0.y, f1.x, f1.y);
}

__device__ __forceinline__ void h16_store4(__half* p, float4 v) {
    h2 a = pk16(v.x, v.y);
    h2 b = pk16(v.z, v.w);
    uint2 r;
    r.x = *reinterpret_cast<uint*>(&a);
    r.y = *reinterpret_cast<uint*>(&b);
    *reinterpret_cast<uint2*>(p) = r;
}

// ---------------- node embedding: h16 = x @ node_w + node_b  [N,14]->[N,32] fp16
__global__ __launch_bounds__(256) void k_node_embed(const float* __restrict__ x,
                                                    const float* __restrict__ w,
                                                    const float* __restrict__ b,
                                                    __half* __restrict__ h16) {
    __shared__ float sw[14 * 32];
    __shared__ float sb[32];
    for (int i = threadIdx.x; i < 14 * 32; i += 256) sw[i] = w[i];
    if (threadIdx.x < 32) sb[threadIdx.x] = b[threadIdx.x];
    __syncthreads();
    int n = blockIdx.x * 256 + threadIdx.x;
    if (n >= NN) return;
    float xi[14];
#pragma unroll
    for (int k = 0; k < 14; ++k) xi[k] = x[n * 14 + k];
#pragma unroll
    for (int c = 0; c < 32; c += 4) {
        float4 acc = make_float4(sb[c], sb[c + 1], sb[c + 2], sb[c + 3]);
#pragma unroll
        for (int k = 0; k < 14; ++k) {
            float xv = xi[k];
            acc.x += xv * sw[k * 32 + c + 0];
            acc.y += xv * sw[k * 32 + c + 1];
            acc.z += xv * sw[k * 32 + c + 2];
            acc.w += xv * sw[k * 32 + c + 3];
        }
        h16_store4(h16 + (size_t)n * 32 + c, acc);
    }
}

// ---------------- weight prep (once): fp16-pack MLP weights, pad j to 76
__global__ __launch_bounds__(256) void k_prep(const float* __restrict__ w1,
                                              const float* __restrict__ b1,
                                              const float* __restrict__ w2,
                                              uint* __restrict__ w1h,
                                              uint* __restrict__ w2p,
                                              float* __restrict__ b1p) {
    int i = blockIdx.x * 256 + threadIdx.x;
    if (i < 2 * 76 * 16) {
        int l = i / (76 * 16), r = i % (76 * 16);
        int j = r / 16, p = r % 16;
        float a = (j < 75) ? w1[l * 2400 + (2 * p) * 75 + j] : 0.f;
        float b = (j < 75) ? w1[l * 2400 + (2 * p + 1) * 75 + j] : 0.f;
        uint lo = __half_as_ushort(__float2half_rn(a));
        uint hi = __half_as_ushort(__float2half_rn(b));
        w1h[i] = lo | (hi << 16);
        return;
    }
    int i2 = i - 2 * 76 * 16;
    if (i2 >= 0 && i2 < 2 * 38 * 32) {
        int l = i2 / (38 * 32), r = i2 % (38 * 32);
        int jp = r / 32, k = r % 32;
        float a = w2[l * 2400 + (2 * jp) * 32 + k];
        float b = (2 * jp + 1 < 75) ? w2[l * 2400 + (2 * jp + 1) * 32 + k] : 0.f;
        uint lo = __half_as_ushort(__float2half_rn(a));
        uint hi = __half_as_ushort(__float2half_rn(b));
        w2p[i2] = lo | (hi << 16);
        return;
    }
    int i3 = i2 - 2 * 38 * 32;
    if (i3 >= 0 && i3 < 2 * 76) {
        int l = i3 / 76, j = i3 % 76;
        b1p[i3] = (j < 75) ? b1[l * 75 + j] : 0.f;
    }
}

// ================= bucket partition + per-bucket sort (once per launch) =========
__global__ __launch_bounds__(1024) void k_hist(const int* __restrict__ ei,
                                               int* __restrict__ counts) {
    __shared__ int hist[NBKT];
    for (int i = threadIdx.x; i < NBKT; i += 1024) hist[i] = 0;
    __syncthreads();
    int base = blockIdx.x * EPB;
#pragma unroll
    for (int k = 0; k < EPB / 1024; ++k) {
        int e = base + k * 1024 + threadIdx.x;
        if (e < NE) atomicAdd(&hist[ei[NE + e] >> 8], 1);
    }
    __syncthreads();
    for (int b = threadIdx.x; b < NBKT; b += 1024)
        counts[b * NPBLK + blockIdx.x] = hist[b];
}

__global__ __launch_bounds__(256) void k_scanA(int* __restrict__ data,
                                               int* __restrict__ part) {
    __shared__ int s[256];
    int tid = threadIdx.x;
    int i = blockIdx.x * 256 + tid;
    int v = (i < SCAN_N) ? data[i] : 0;
    s[tid] = v;
    __syncthreads();
    for (int off = 1; off < 256; off <<= 1) {
        int t = (tid >= off) ? s[tid - off] : 0;
        __syncthreads();
        s[tid] += t;
        __syncthreads();
    }
    if (i < SCAN_N) data[i] = s[tid] - v;
    if (tid == 255) part[blockIdx.x] = s[255];
}

__global__ __launch_bounds__(1024) void k_scanB(int* __restrict__ part) {
    __shared__ int s[1024];
    int tid = threadIdx.x;
    int v = (tid < NSB1) ? part[tid] : 0;
    s[tid] = v;
    __syncthreads();
    for (int off = 1; off < 1024; off <<= 1) {
        int t = (tid >= off) ? s[tid - off] : 0;
        __syncthreads();
        s[tid] += t;
        __syncthreads();
    }
    if (tid < NSB1) part[tid] = s[tid] - v;
}

// rec = { src | nl<<24, half2(ea0,ea1), half(ea2) }  — 1024 threads/block
// scanC fused: global base = counts[idx] + part[idx>>8]
__global__ __launch_bounds__(1024) void k_part_scatter(const int* __restrict__ ei,
                                                       const float* __restrict__ ea,
                                                       const int* __restrict__ counts,
                                                       const int* __restrict__ part,
                                                       uint3* __restrict__ tmp) {
    __shared__ int sbase[NBKT];
    __shared__ int scnt[NBKT];
    for (int i = threadIdx.x; i < NBKT; i += 1024) {
        int idx = i * NPBLK + blockIdx.x;
        sbase[i] = counts[idx] + part[idx >> 8];
        scnt[i] = 0;
    }
    __syncthreads();
    int base = blockIdx.x * EPB;
#pragma unroll
    for (int k = 0; k < EPB / 1024; ++k) {
        int e = base + k * 1024 + threadIdx.x;
        if (e >= NE) continue;
        int dst = ei[NE + e];
        int bkt = dst >> 8;
        int nl = dst & 255;
        int r = atomicAdd(&scnt[bkt], 1);
        int src = ei[e];
        __half2 p01 = __floats2half2_rn(ea[e * 3 + 0], ea[e * 3 + 1]);
        __half p2 = __float2half_rn(ea[e * 3 + 2]);
        uint3 rec;
        rec.x = (uint)(src | (nl << 24));
        rec.y = *reinterpret_cast<const uint*>(&p01);
        rec.z = (uint)__half_as_ushort(p2);
        tmp[sbase[bkt] + r] = rec;
    }
}

// per-bucket LDS counting sort -> exact node-sorted recs2 + row_off
__global__ __launch_bounds__(512) void k_bucket_sort(const int* __restrict__ counts,
                                                     const int* __restrict__ part,
                                                     const uint3* __restrict__ tmp,
                                                     uint3* __restrict__ recs2,
                                                     int* __restrict__ row_off) {
    __shared__ int cnt[NPB];
    __shared__ int s[NPB];
    int tid = threadIdx.x;
    int b = blockIdx.x;
    int idx0 = b * NPBLK;
    int boff = counts[idx0] + part[idx0 >> 8];
    int bend;
    if (b == NBKT - 1) {
        bend = NE;
    } else {
        int idx1 = (b + 1) * NPBLK;
        bend = counts[idx1] + part[idx1 >> 8];
    }
    if (tid < NPB) cnt[tid] = 0;
    __syncthreads();
    for (int i = boff + tid; i < bend; i += 512)
        atomicAdd(&cnt[(tmp[i].x >> 24) & 255], 1);
    __syncthreads();
    int v = (tid < NPB) ? cnt[tid] : 0;
    if (tid < NPB) s[tid] = v;
    __syncthreads();
    for (int off = 1; off < 256; off <<= 1) {
        int t = (tid >= off && tid < NPB) ? s[tid - off] : 0;
        __syncthreads();
        if (tid < NPB) s[tid] += t;
        __syncthreads();
    }
    if (tid < NPB) {
        int excl = s[tid] - v;
        int n = b * NPB + tid;
        if (n < NN) row_off[n] = boff + excl;
        cnt[tid] = excl;  // becomes fill counter
    }
    if (b == NBKT - 1 && tid == 0) row_off[NN] = NE;
    __syncthreads();
    for (int i = boff + tid; i < bend; i += 512) {
        uint3 r = tmp[i];
        int nl = (r.x >> 24) & 255;
        int p = atomicAdd(&cnt[nl], 1);
        recs2[boff + p] = r;
    }
}

// shared helper: per-block BN affine preamble into LDS (sc,sh per channel)
__device__ __forceinline__ void bn_preamble(float* ssc, float* ssh, int apply,
                                            const float* in_stats,
                                            const float* in_g, const float* in_b) {
    if (threadIdx.x < 32) {
        float s = 1.f, t = 0.f;
        if (apply) {
            int cc = threadIdx.x;
            float mu = in_stats[cc] * (1.0f / NN);
            float var = in_stats[32 + cc] * (1.0f / NN) - mu * mu;
            s = in_g[cc] * rsqrtf(var + 1e-5f);
            t = in_b[cc] - mu * s;
        }
        ssc[threadIdx.x] = s;
        ssh[threadIdx.x] = t;
    }
}

// ---------------- exact-CSR gather aggregation: 8 thr/node, 8B fp16 z gathers.
// Applies h = APPLY ? relu(z*sc+sh) : z on the fly, ADDS OWN NODE's h, and
// writes z0 as FP16 (identical rounding to the old fp32-write + mlp-pack path).
template <int APPLY>
__global__ __launch_bounds__(256) void k_aggregate(const int* __restrict__ row_off,
                                                   const uint3* __restrict__ recs,
                                                   const float* __restrict__ ew,
                                                   const float* __restrict__ eb,
                                                   const __half* __restrict__ h16,
                                                   const float* __restrict__ in_stats,
                                                   const float* __restrict__ in_g,
                                                   const float* __restrict__ in_b,
                                                   __half* __restrict__ z16) {
    __shared__ float sw[96];
    __shared__ float sb[32];
    __shared__ float ssc[32], ssh[32];
    if (threadIdx.x < 96) sw[threadIdx.x] = ew[threadIdx.x];
    if (threadIdx.x < 32) sb[threadIdx.x] = eb[threadIdx.x];
    bn_preamble(ssc, ssh, APPLY, in_stats, in_g, in_b);
    __syncthreads();
    int t = blockIdx.x * 256 + threadIdx.x;
    int n = t >> 3;
    if (n >= NN) return;
    int c = (t & 7) * 4;  // 4 channels per thread
    float w0[4], w1[4], w2[4], bb[4], acc[4], sc4[4], sh4[4];
#pragma unroll
    for (int j = 0; j < 4; ++j) {
        w0[j] = sw[c + j];
        w1[j] = sw[32 + c + j];
        w2[j] = sw[64 + c + j];
        bb[j] = sb[c + j];
        sc4[j] = ssc[c + j];
        sh4[j] = ssh[c + j];
        acc[j] = 0.f;
    }
    int s0 = row_off[n], s1 = row_off[n + 1];
    int i = s0;
    for (; i + 2 <= s1; i += 2) {
        uint3 r0 = recs[i];
        uint3 r1 = recs[i + 1];
        int src0 = r0.x & 0x00FFFFFF;
        int src1 = r1.x & 0x00FFFFFF;
        uint2 ha = *(const uint2*)(h16 + (size_t)src0 * 32 + c);
        uint2 hb = *(const uint2*)(h16 + (size_t)src1 * 32 + c);
        float2 e01a = __half22float2(*reinterpret_cast<const __half2*>(&r0.y));
        float e2a = __half2float(__ushort_as_half((unsigned short)(r0.z & 0xFFFF)));
        float2 e01b = __half22float2(*reinterpret_cast<const __half2*>(&r1.y));
        float e2b = __half2float(__ushort_as_half((unsigned short)(r1.z & 0xFFFF)));
        float fa[4], fb[4];
        {
            float2 t0 = __half22float2(*reinterpret_cast<const __half2*>(&ha.x));
            float2 t1 = __half22float2(*reinterpret_cast<const __half2*>(&ha.y));
            fa[0] = t0.x; fa[1] = t0.y; fa[2] = t1.x; fa[3] = t1.y;
            float2 u0 = __half22float2(*reinterpret_cast<const __half2*>(&hb.x));
            float2 u1 = __half22float2(*reinterpret_cast<const __half2*>(&hb.y));
            fb[0] = u0.x; fb[1] = u0.y; fb[2] = u1.x; fb[3] = u1.y;
        }
#pragma unroll
        for (int j = 0; j < 4; ++j) {
            float va = fa[j], vb = fb[j];
            if (APPLY) {
                va = fmaxf(va * sc4[j] + sh4[j], 0.f);
                vb = fmaxf(vb * sc4[j] + sh4[j], 0.f);
            }
            float ma = va + bb[j] + e01a.x * w0[j] + e01a.y * w1[j] + e2a * w2[j];
            float mb = vb + bb[j] + e01b.x * w0[j] + e01b.y * w1[j] + e2b * w2[j];
            acc[j] += fmaxf(ma, 0.f) + fmaxf(mb, 0.f);
        }
    }
    if (i < s1) {
        uint3 r0 = recs[i];
        int src0 = r0.x & 0x00FFFFFF;
        uint2 ha = *(const uint2*)(h16 + (size_t)src0 * 32 + c);
        float2 e01a = __half22float2(*reinterpret_cast<const __half2*>(&r0.y));
        float e2a = __half2float(__ushort_as_half((unsigned short)(r0.z & 0xFFFF)));
        float2 t0 = __half22float2(*reinterpret_cast<const __half2*>(&ha.x));
        float2 t1 = __half22float2(*reinterpret_cast<const __half2*>(&ha.y));
        float fa[4] = {t0.x, t0.y, t1.x, t1.y};
#pragma unroll
        for (int j = 0; j < 4; ++j) {
            float va = fa[j];
            if (APPLY) va = fmaxf(va * sc4[j] + sh4[j], 0.f);
            float ma = va + bb[j] + e01a.x * w0[j] + e01a.y * w1[j] + e2a * w2[j];
            acc[j] += fmaxf(ma, 0.f);
        }
    }
    // add own node's h (affine) so z16 = complete z0 = h[n] + agg
    {
        uint2 hn = *(const uint2*)(h16 + (size_t)n * 32 + c);
        float2 t0 = __half22float2(*reinterpret_cast<const __half2*>(&hn.x));
        float2 t1 = __half22float2(*reinterpret_cast<const __half2*>(&hn.y));
        float fn[4] = {t0.x, t0.y, t1.x, t1.y};
#pragma unroll
        for (int j = 0; j < 4; ++j) {
            float vn = fn[j];
            if (APPLY) vn = fmaxf(vn * sc4[j] + sh4[j], 0.f);
            acc[j] += vn;
        }
    }
    // fp16 pack + 8B store (identical rounding to old mlp-side pack)
    h2 pa = pk16(acc[0], acc[1]);
    h2 pb = pk16(acc[2], acc[3]);
    uint2 r;
    r.x = *reinterpret_cast<uint*>(&pa);
    r.y = *reinterpret_cast<uint*>(&pb);
    *reinterpret_cast<uint2*>(z16 + (size_t)n * 32 + c) = r;
}

// ---------------- fallback atomic scatter (only if ws too small)
__global__ __launch_bounds__(256) void k_edge_scatter(const int* __restrict__ ei,
                                                      const float* __restrict__ ea,
                                                      const float* __restrict__ ew,
                                                      const float* __restrict__ eb,
                                                      const __half* __restrict__ h16,
                                                      const float* __restrict__ in_stats,
                                                      const float* __restrict__ in_g,
                                                      const float* __restrict__ in_b,
                                                      int apply,
                                                      float* __restrict__ agg) {
    __shared__ float sw[96];
    __shared__ float sb[32];
    __shared__ float ssc[32], ssh[32];
    if (threadIdx.x < 96) sw[threadIdx.x] = ew[threadIdx.x];
    if (threadIdx.x < 32) sb[threadIdx.x] = eb[threadIdx.x];
    bn_preamble(ssc, ssh, apply, in_stats, in_g, in_b);
    __syncthreads();
    int t = blockIdx.x * 256 + threadIdx.x;
    int edge = t >> 3;
    if (edge >= NE) return;
    int c = (t & 7) * 4;
    int src = ei[edge];
    int dst = ei[NE + edge];
    float a0 = ea[edge * 3 + 0];
    float a1 = ea[edge * 3 + 1];
    float a2 = ea[edge * 3 + 2];
    float4 hs = h16_load4(h16 + (size_t)src * 32 + c);
    if (apply) {
        hs.x = fmaxf(hs.x * ssc[c + 0] + ssh[c + 0], 0.f);
        hs.y = fmaxf(hs.y * ssc[c + 1] + ssh[c + 1], 0.f);
        hs.z = fmaxf(hs.z * ssc[c + 2] + ssh[c + 2], 0.f);
        hs.w = fmaxf(hs.w * ssc[c + 3] + ssh[c + 3], 0.f);
    }
    float m0 = hs.x + sb[c + 0] + a0 * sw[c + 0] + a1 * sw[32 + c + 0] + a2 * sw[64 + c + 0];
    float m1 = hs.y + sb[c + 1] + a0 * sw[c + 1] + a1 * sw[32 + c + 1] + a2 * sw[64 + c + 1];
    float m2 = hs.z + sb[c + 2] + a0 * sw[c + 2] + a1 * sw[32 + c + 2] + a2 * sw[64 + c + 2];
    float m3 = hs.w + sb[c + 3] + a0 * sw[c + 3] + a1 * sw[32 + c + 3] + a2 * sw[64 + c + 3];
    float* o = agg + (size_t)dst * 32 + c;
    fadd(o + 0, fmaxf(m0, 0.f));
    fadd(o + 1, fmaxf(m1, 0.f));
    fadd(o + 2, fmaxf(m2, 0.f));
    fadd(o + 3, fmaxf(m3, 0.f));
}

// ---------------- own-node add for fallback path (zb += h_affine[n])
__global__ __launch_bounds__(256) void k_self_add(const __half* __restrict__ h16,
                                                  const float* __restrict__ in_stats,
                                                  const float* __restrict__ in_g,
                                                  const float* __restrict__ in_b,
                                                  int apply,
                                                  float* __restrict__ agg) {
    __shared__ float ssc[32], ssh[32];
    bn_preamble(ssc, ssh, apply, in_stats, in_g, in_b);
    __syncthreads();
    int i = blockIdx.x * 256 + threadIdx.x;
    if (i >= NN * 8) return;
    int c = (i & 7) * 4;
    float4 v = h16_load4(h16 + (size_t)i * 4);
    if (apply) {
        v.x = fmaxf(v.x * ssc[c + 0] + ssh[c + 0], 0.f);
        v.y = fmaxf(v.y * ssc[c + 1] + ssh[c + 1], 0.f);
        v.z = fmaxf(v.z * ssc[c + 2] + ssh[c + 2], 0.f);
        v.w = fmaxf(v.w * ssc[c + 3] + ssh[c + 3], 0.f);
    }
    float4 a = *(const float4*)(agg + (size_t)i * 4);
    *(float4*)(agg + (size_t)i * 4) = make_float4(a.x + v.x, a.y + v.y, a.z + v.z, a.w + v.w);
}

// ---------------- node MLP + fused BN stats; 2 NODES/THREAD, weights in LDS.
// Z16=1: z input is fp16 (fast path, loads feed dot2 directly).
// Z16=0: z input is fp32 (fallback), packed on the fly.
template <int Z16>
__global__ __launch_bounds__(256) void k_mlp_stats(__half* __restrict__ hio,
                                                   const void* __restrict__ zin,
                                                   const uint* __restrict__ w1h_u,
                                                   const float* __restrict__ b1p_g,
                                                   const uint* __restrict__ w2p_u,
                                                   const float* __restrict__ b2_g,
                                                   float* __restrict__ stats) {
    __shared__ float ls[4][64];
    __shared__ uint sw1[76 * 16];   // 1216 dwords
    __shared__ uint sw2[38 * 32];   // 1216 dwords
    __shared__ float sb1[76];
    __shared__ float sb2[32];
    int tid = threadIdx.x;
    for (int i = tid; i < 1216; i += 256) {
        sw1[i] = w1h_u[i];
        sw2[i] = w2p_u[i];
    }
    if (tid < 76) sb1[tid] = b1p_g[tid];
    if (tid < 32) sb2[tid] = b2_g[tid];
    __syncthreads();
    const h2* w1h = reinterpret_cast<const h2*>(sw1);
    const h2* w2p = reinterpret_cast<const h2*>(sw2);
    int n0 = blockIdx.x * 512 + tid;
    int n1 = n0 + 256;
    bool v0 = n0 < NN, v1 = n1 < NN;
    h2 zp0[16], zp1[16];
    float acc0[32], acc1[32];
    if (Z16) {
        const __half* z16 = (const __half*)zin;
        if (v0) {
#pragma unroll
            for (int q = 0; q < 4; ++q) {
                uint4 r = *(const uint4*)(z16 + (size_t)n0 * 32 + q * 8);
                zp0[q * 4 + 0] = *reinterpret_cast<h2*>(&r.x);
                zp0[q * 4 + 1] = *reinterpret_cast<h2*>(&r.y);
                zp0[q * 4 + 2] = *reinterpret_cast<h2*>(&r.z);
                zp0[q * 4 + 3] = *reinterpret_cast<h2*>(&r.w);
            }
        } else {
#pragma unroll
            for (int p = 0; p < 16; ++p) zp0[p] = pk16(0.f, 0.f);
        }
        if (v1) {
#pragma unroll
            for (int q = 0; q < 4; ++q) {
                uint4 r = *(const uint4*)(z16 + (size_t)n1 * 32 + q * 8);
                zp1[q * 4 + 0] = *reinterpret_cast<h2*>(&r.x);
                zp1[q * 4 + 1] = *reinterpret_cast<h2*>(&r.y);
                zp1[q * 4 + 2] = *reinterpret_cast<h2*>(&r.z);
                zp1[q * 4 + 3] = *reinterpret_cast<h2*>(&r.w);
            }
        } else {
#pragma unroll
            for (int p = 0; p < 16; ++p) zp1[p] = pk16(0.f, 0.f);
        }
    } else {
        const float* zf = (const float*)zin;
        if (v0) {
#pragma unroll
            for (int c = 0; c < 32; c += 4) {
                float4 av = *(const float4*)(zf + (size_t)n0 * 32 + c);
                zp0[c / 2] = pk16(av.x, av.y);
                zp0[c / 2 + 1] = pk16(av.z, av.w);
            }
        } else {
#pragma unroll
            for (int p = 0; p < 16; ++p) zp0[p] = pk16(0.f, 0.f);
        }
        if (v1) {
#pragma unroll
            for (int c = 0; c < 32; c += 4) {
                float4 av = *(const float4*)(zf + (size_t)n1 * 32 + c);
                zp1[c / 2] = pk16(av.x, av.y);
                zp1[c / 2 + 1] = pk16(av.z, av.w);
            }
        } else {
#pragma unroll
            for (int p = 0; p < 16; ++p) zp1[p] = pk16(0.f, 0.f);
        }
    }
#pragma unroll
    for (int k = 0; k < 32; ++k) {
        acc0[k] = sb2[k];
        acc1[k] = sb2[k];
    }
    for (int jp = 0; jp < 38; ++jp) {
        float b1a = sb1[2 * jp], b1b = sb1[2 * jp + 1];
        float s0a = b1a, s0b = 0.f, s1a = b1b, s1b = 0.f;      // node 0
        float u0a = b1a, u0b = 0.f, u1a = b1b, u1b = 0.f;      // node 1
        const h2* r0 = w1h + (2 * jp) * 16;
        const h2* r1 = w1h + (2 * jp + 1) * 16;
#pragma unroll
        for (int p = 0; p < 8; ++p) {
            h2 wa0 = r0[2 * p], wa1 = r0[2 * p + 1];
            h2 wb0 = r1[2 * p], wb1 = r1[2 * p + 1];
            s0a = fdot2(zp0[2 * p], wa0, s0a);
            s0b = fdot2(zp0[2 * p + 1], wa1, s0b);
            s1a = fdot2(zp0[2 * p], wb0, s1a);
            s1b = fdot2(zp0[2 * p + 1], wb1, s1b);
            u0a = fdot2(zp1[2 * p], wa0, u0a);
            u0b = fdot2(zp1[2 * p + 1], wa1, u0b);
            u1a = fdot2(zp1[2 * p], wb0, u1a);
            u1b = fdot2(zp1[2 * p + 1], wb1, u1b);
        }
        h2 tp0 = pk16(fmaxf(s0a + s0b, 0.f), fmaxf(s1a + s1b, 0.f));
        h2 tp1 = pk16(fmaxf(u0a + u0b, 0.f), fmaxf(u1a + u1b, 0.f));
        const h2* c2 = w2p + jp * 32;
#pragma unroll
        for (int k = 0; k < 32; ++k) {
            h2 wk = c2[k];
            acc0[k] = fdot2(tp0, wk, acc0[k]);
            acc1[k] = fdot2(tp1, wk, acc1[k]);
        }
    }
    if (v0) {
#pragma unroll
        for (int c = 0; c < 32; c += 4)
            h16_store4(hio + (size_t)n0 * 32 + c,
                       make_float4(acc0[c], acc0[c + 1], acc0[c + 2], acc0[c + 3]));
    } else {
#pragma unroll
        for (int k = 0; k < 32; ++k) acc0[k] = 0.f;
    }
    if (v1) {
#pragma unroll
        for (int c = 0; c < 32; c += 4)
            h16_store4(hio + (size_t)n1 * 32 + c,
                       make_float4(acc1[c], acc1[c + 1], acc1[c + 2], acc1[c + 3]));
    } else {
#pragma unroll
        for (int k = 0; k < 32; ++k) acc1[k] = 0.f;
    }
    // fused BN statistics over both nodes: butterfly over 64 lanes, per channel
    int wave = tid >> 6, lane = tid & 63;
#pragma unroll
    for (int k = 0; k < 32; ++k) {
        float sv = acc0[k] + acc1[k];
        float qv = acc0[k] * acc0[k] + acc1[k] * acc1[k];
#pragma unroll
        for (int off = 1; off < 64; off <<= 1) {
            sv += __shfl_xor(sv, off);
            qv += __shfl_xor(qv, off);
        }
        if (lane == 0) {
            ls[wave][k] = sv;
            ls[wave][32 + k] = qv;
        }
    }
    __syncthreads();
    if (tid < 64)
        fadd(&stats[tid], ls[0][tid] + ls[1][tid] + ls[2][tid] + ls[3][tid]);
}

// ---------------- pool: batch sorted — affine+relu on the fly, flush per boundary
__global__ __launch_bounds__(256) void k_pool(const __half* __restrict__ h16,
                                              const int* __restrict__ batch,
                                              const float* __restrict__ in_stats,
                                              const float* __restrict__ in_g,
                                              const float* __restrict__ in_b,
                                              float* __restrict__ gsum,
                                              float* __restrict__ gcnt) {
    __shared__ float ssc[32], ssh[32];
    bn_preamble(ssc, ssh, 1, in_stats, in_g, in_b);
    __syncthreads();
    int gid = blockIdx.x * 256 + threadIdx.x;
    int nb = (gid >> 3) * 8;
    if (nb >= NN) return;
    int c = (gid & 7) * 4;
    bool lead = (gid & 7) == 0;
    float sc0 = ssc[c], sc1 = ssc[c + 1], sc2 = ssc[c + 2], sc3 = ssc[c + 3];
    float sh0 = ssh[c], sh1 = ssh[c + 1], sh2 = ssh[c + 2], sh3 = ssh[c + 3];
    float4 acc = make_float4(0.f, 0.f, 0.f, 0.f);
    float cnt = 0.f;
    int cur = batch[nb];
#pragma unroll
    for (int k = 0; k < 8; ++k) {
        int n = nb + k;
        if (n >= NN) break;
        int bg = batch[n];
        if (bg != cur) {
            float* o = gsum + (size_t)cur * 32 + c;
            fadd(o + 0, acc.x); fadd(o + 1, acc.y);
            fadd(o + 2, acc.z); fadd(o + 3, acc.w);
            if (lead) fadd(&gcnt[cur], cnt);
            acc = make_float4(0.f, 0.f, 0.f, 0.f);
            cnt = 0.f;
            cur = bg;
        }
        float4 v = h16_load4(h16 + (size_t)n * 32 + c);
        acc.x += fmaxf(v.x * sc0 + sh0, 0.f);
        acc.y += fmaxf(v.y * sc1 + sh1, 0.f);
        acc.z += fmaxf(v.z * sc2 + sh2, 0.f);
        acc.w += fmaxf(v.w * sc3 + sh3, 0.f);
        cnt += 1.f;
    }
    float* o = gsum + (size_t)cur * 32 + c;
    fadd(o + 0, acc.x); fadd(o + 1, acc.y);
    fadd(o + 2, acc.z); fadd(o + 3, acc.w);
    if (lead) fadd(&gcnt[cur], cnt);
}

__global__ __launch_bounds__(256) void k_head(const float* __restrict__ gsum,
                                              const float* __restrict__ gcnt,
                                              const float* __restrict__ l1w,
                                              const float* __restrict__ l1b,
                                              const float* __restrict__ l2w,
                                              const float* __restrict__ l2b,
                                              float* __restrict__ out) {
    __shared__ float s1[32 * 16], sb1[16], s2[16 * 2], sb2[2];
    for (int i = threadIdx.x; i < 512; i += 256) s1[i] = l1w[i];
    if (threadIdx.x < 16) sb1[threadIdx.x] = l1b[threadIdx.x];
    if (threadIdx.x < 32) s2[threadIdx.x] = l2w[threadIdx.x];
    if (threadIdx.x < 2) sb2[threadIdx.x] = l2b[threadIdx.x];
    __syncthreads();
    int gi = blockIdx.x * 256 + threadIdx.x;
    if (gi >= NG) return;
    float inv = 1.0f / fmaxf(gcnt[gi], 1.0f);
    float gm[32];
#pragma unroll
    for (int c = 0; c < 32; c += 4) {
        float4 v = *(const float4*)(gsum + (size_t)gi * 32 + c);
        gm[c + 0] = v.x * inv;
        gm[c + 1] = v.y * inv;
        gm[c + 2] = v.z * inv;
        gm[c + 3] = v.w * inv;
    }
    float a[16];
#pragma unroll
    for (int j = 0; j < 16; ++j) {
        float t = sb1[j];
#pragma unroll
        for (int c = 0; c < 32; ++c) t += gm[c] * s1[c * 16 + j];
        a[j] = fmaxf(t, 0.f);
    }
    float o0 = sb2[0], o1 = sb2[1];
#pragma unroll
    for (int j = 0; j < 16; ++j) {
        o0 += a[j] * s2[j * 2 + 0];
        o1 += a[j] * s2[j * 2 + 1];
    }
    out[gi * 2 + 0] = o0;
    out[gi * 2 + 1] = o1;
}

extern "C" void kernel_launch(void* const* d_in, const int* in_sizes, int n_in,
                              void* d_out, int out_size, void* d_ws, size_t ws_size,
                              hipStream_t stream) {
    const float* x = (const float*)d_in[0];
    const int* ei = (const int*)d_in[1];
    const float* ea = (const float*)d_in[2];
    const int* batch = (const int*)d_in[3];
    const float* node_w = (const float*)d_in[4];
    const float* node_b = (const float*)d_in[5];
    const float* edge_w = (const float*)d_in[6];
    const float* edge_b = (const float*)d_in[7];
    const float* w1 = (const float*)d_in[8];
    const float* b1 = (const float*)d_in[9];
    const float* w2 = (const float*)d_in[10];
    const float* b2 = (const float*)d_in[11];
    const float* bng = (const float*)d_in[12];
    const float* bnb = (const float*)d_in[13];
    const float* l1w = (const float*)d_in[14];
    const float* l1b = (const float*)d_in[15];
    const float* l2w = (const float*)d_in[16];
    const float* l2b = (const float*)d_in[17];
    float* out = (float*)d_out;

    // workspace layout (float units); zb region reserved at NN*32 floats so the
    // fallback can use it as fp32; fast path uses the first half as fp16 z16.
    float* base = (float*)d_ws;
    __half* h16 = (__half*)base;                   // NN*32 halves = 3.2M floats (z16 out)
    float* zb = base + 3200000;                    // region: NN*32 floats (aliases tmp)
    __half* z16 = (__half*)zb;                     // fast path: NN*32 halves
    float* gsum = zb + (size_t)NN * 32;            // NG*32
    float* gcnt = gsum + (size_t)NG * 32;          // NG
    float* stats = gcnt + NG;                      // 2*64 (per layer)
    uint* w1h = (uint*)(stats + 128);              // 2*76*16 = 2432
    uint* w2p = w1h + 2 * 76 * 16;                 // 2*38*32 = 2432
    float* b1p = (float*)(w2p + 2 * 38 * 32);      // 152
    int* counts = (int*)(b1p + 152);               // SCAN_PAD
    int* part = counts + SCAN_PAD;                 // 1024
    int* row_off = part + 1024;                    // NN+4
    uint3* recs2 = (uint3*)(row_off + NN + 4);     // NE*3 uints
    uint3* tmp = (uint3*)zb;                       // NE*3 = 6.0M <= 6.4M floats

    size_t need_f = 3200000 + (size_t)NN * 32 + (size_t)NG * 33 + 128 + 2432 + 2432 + 152 +
                    SCAN_PAD + 1024 + ((size_t)NN + 4) + (size_t)NE * 3;
    bool use_fast = ws_size >= need_f * 4;

    if (use_fast) {
        k_hist<<<NPBLK, 1024, 0, stream>>>(ei, counts);
        k_scanA<<<NSB1, 256, 0, stream>>>(counts, part);
        k_scanB<<<1, 1024, 0, stream>>>(part);
        k_part_scatter<<<NPBLK, 1024, 0, stream>>>(ei, ea, counts, part, tmp);
        k_bucket_sort<<<NBKT, 512, 0, stream>>>(counts, part, tmp, recs2, row_off);
    }
    k_prep<<<(2 * 76 * 16 + 2 * 38 * 32 + 2 * 76 + 255) / 256, 256, 0, stream>>>(
        w1, b1, w2, w1h, w2p, b1p);

    k_node_embed<<<(NN + 255) / 256, 256, 0, stream>>>(x, node_w, node_b, h16);

    (void)hipMemsetAsync(stats, 0, 128 * sizeof(float), stream);

    for (int l = 0; l < 2; ++l) {
        int apply = (l > 0) ? 1 : 0;
        const float* prev_stats = (l > 0) ? (stats + (l - 1) * 64) : stats;
        const float* ig = (l > 0) ? (bng + (l - 1) * 32) : bng;  // unused when apply=0
        const float* ib = (l > 0) ? (bnb + (l - 1) * 32) : bnb;
        if (use_fast) {
            if (apply)
                k_aggregate<1><<<(NN * 8 + 255) / 256, 256, 0, stream>>>(row_off, recs2,
                                                                         edge_w, edge_b, h16,
                                                                         prev_stats, ig, ib, z16);
            else
                k_aggregate<0><<<(NN * 8 + 255) / 256, 256, 0, stream>>>(row_off, recs2,
                                                                         edge_w, edge_b, h16,
                                                                         prev_stats, ig, ib, z16);
            k_mlp_stats<1><<<(NN + 511) / 512, 256, 0, stream>>>(h16, z16, w1h + l * 76 * 16,
                                                                 b1p + l * 76, w2p + l * 38 * 32,
                                                                 b2 + l * 32, stats + l * 64);
        } else {
            (void)hipMemsetAsync(zb, 0, (size_t)NN * 32 * sizeof(float), stream);
            k_edge_scatter<<<(NE * 8) / 256, 256, 0, stream>>>(ei, ea, edge_w, edge_b, h16,
                                                               prev_stats, ig, ib, apply, zb);
            k_self_add<<<(NN * 8 + 255) / 256, 256, 0, stream>>>(h16, prev_stats, ig, ib,
                                                                 apply, zb);
            k_mlp_stats<0><<<(NN + 511) / 512, 256, 0, stream>>>(h16, zb, w1h + l * 76 * 16,
                                                                 b1p + l * 76, w2p + l * 38 * 32,
                                                                 b2 + l * 32, stats + l * 64);
        }
    }

    (void)hipMemsetAsync(gsum, 0, (size_t)(NG * 33) * sizeof(float), stream);
    k_pool<<<(NN + 255) / 256, 256, 0, stream>>>(h16, batch, stats + 64, bng + 32, bnb + 32,
                                                 gsum, gcnt);
    k_head<<<(NG + 255) / 256, 256, 0, stream>>>(gsum, gcnt, l1w, l1b, l2w, l2b, out);
}